// Round 3
// baseline (3067.413 us; speedup 1.0000x reference)
//
#include <hip/hip_runtime.h>
#include <hip/hip_bf16.h>

typedef unsigned short u16;
typedef unsigned int u32;

#define B_ 64
#define N_ 64
#define FA_ 75
#define FP_ 14
#define C_ 128

// Static device scratch (not d_ws; fully rewritten each call).
__device__ float g_A0[4096 * 128];   // a0 = mlp2(atom_x, a2a), fp32
__device__ float g_A1[4096 * 128];   // a1 = sum_j mlp2(pair, p2a), fp32
__device__ float g_TB[4096 * 256];   // [T | Bo] = atom @ a2pW0_{top,bot}, fp32
__device__ int   g_isbf;             // runtime-detected input dtype: 1=bf16, 0=fp32

__device__ __forceinline__ float bf2f(u16 a) {
    union { u32 u; float f; } v; v.u = ((u32)a) << 16; return v.f;
}
__device__ __forceinline__ u16 f2bf(float f) {
    union { float f; u32 u; } v; v.f = f;
    u32 r = v.u + 0x7fffu + ((v.u >> 16) & 1u);   // RNE
    return (u16)(r >> 16);
}
__device__ __forceinline__ float uhi(u32 p) { union { u32 u; float f; } v; v.u = p & 0xffff0000u; return v.f; }
__device__ __forceinline__ float ulo(u32 p) { union { u32 u; float f; } v; v.u = p << 16; return v.f; }

// dtype-dispatched element accessors (isbf is wave-uniform; explicit branch so
// only one path's loads ever execute — no speculative OOB reads).
__device__ __forceinline__ u16 ldw(const void* p, size_t i, bool isbf) {
    if (isbf) return ((const u16*)p)[i];
    return f2bf(((const float*)p)[i]);
}
__device__ __forceinline__ float ldf(const void* p, size_t i, bool isbf) {
    if (isbf) return bf2f(((const u16*)p)[i]);
    return ((const float*)p)[i];
}
__device__ __forceinline__ void stout(void* p, size_t i, float v, bool isbf) {
    if (isbf) ((u16*)p)[i] = f2bf(v);
    else      ((float*)p)[i] = v;
}

// Detect input dtype from atom_x: low halfword of each u32 word is a bf16
// N(0,1) sample (sane exponent) if bf16, or uniform fp32 mantissa bits if fp32.
__global__ void detect_k(const void* __restrict__ atom) {
    if (threadIdx.x == 0) {
        const u32* a = (const u32*)atom;
        int sane = 0;
        for (int w = 0; w < 64; ++w) {
            u32 ex = (a[w] >> 7) & 0xffu;          // exponent of LOW bf16
            sane += (ex >= 113u && ex <= 133u) ? 1 : 0;
        }
        g_isbf = (sane >= 32) ? 1 : 0;
    }
}

// acc[rr] += sum_k A[(r0+rr)*ldA + k] * W[k*128 + c]   (A, W bf16 in LDS)
template<int ROWS>
__device__ __forceinline__ void gemm_k(const u16* __restrict__ A, int ldA, int r0,
                                       const u16* __restrict__ W, int K, int c,
                                       float (&acc)[ROWS]) {
    int k = 0;
    for (; k + 1 < K; k += 2) {
        float w0 = bf2f(W[k * 128 + c]);
        float w1 = bf2f(W[(k + 1) * 128 + c]);
#pragma unroll
        for (int rr = 0; rr < ROWS; ++rr) {
            u32 pa = *(const u32*)&A[(r0 + rr) * ldA + k];
            acc[rr] = fmaf(ulo(pa), w0, acc[rr]);
            acc[rr] = fmaf(uhi(pa), w1, acc[rr]);
        }
    }
    if (k < K) {
        float w = bf2f(W[k * 128 + c]);
#pragma unroll
        for (int rr = 0; rr < ROWS; ++rr)
            acc[rr] = fmaf(bf2f(A[(r0 + rr) * ldA + k]), w, acc[rr]);
    }
}

// fp32 A-operand variant (A in LDS as float).
template<int ROWS>
__device__ __forceinline__ void gemm_kf(const float* __restrict__ A, int ldA, int r0,
                                        const u16* __restrict__ W, int K, int c,
                                        float (&acc)[ROWS]) {
    for (int k = 0; k < K; ++k) {
        float w = bf2f(W[k * 128 + c]);
#pragma unroll
        for (int rr = 0; rr < ROWS; ++rr)
            acc[rr] = fmaf(A[(r0 + rr) * ldA + k], w, acc[rr]);
    }
}

// ---------------- Kernel 1: atom branch pre-work ----------------
__global__ __launch_bounds__(256) void atom_pre(
    const void* __restrict__ atom,
    const void* __restrict__ aaW0, const void* __restrict__ aaB0,
    const void* __restrict__ aaW1, const void* __restrict__ aaB1,
    const void* __restrict__ apW0) {
    __shared__ u16 sX[64][76];
    __shared__ u16 sW[150 * 128];
    __shared__ u16 sH[64][128];
    const bool isbf = g_isbf != 0;
    const int t = threadIdx.x;
    const int b = blockIdx.x;
    for (int idx = t; idx < 64 * FA_; idx += 256) {
        int r = idx / FA_, k = idx - r * FA_;
        sX[r][k] = ldw(atom, (size_t)(b * 64 + r) * FA_ + k, isbf);
    }
    if (t < 64) sX[t][FA_] = 0;
    for (int idx = t; idx < FA_ * 128; idx += 256) sW[idx] = ldw(aaW0, idx, isbf);
    __syncthreads();
    const int c = t & 127, rh = t >> 7;
    {
        float acc[32];
#pragma unroll
        for (int rr = 0; rr < 32; ++rr) acc[rr] = 0.f;
        gemm_k<32>(&sX[0][0], 76, rh * 32, sW, FA_, c, acc);
        float b0 = ldf(aaB0, c, isbf);
#pragma unroll
        for (int rr = 0; rr < 32; ++rr) {
            float v = acc[rr] + b0;
            sH[rh * 32 + rr][c] = f2bf(v > 0.f ? v : 0.f);
        }
    }
    __syncthreads();
    for (int idx = t; idx < 128 * 128; idx += 256) sW[idx] = ldw(aaW1, idx, isbf);
    __syncthreads();
    {
        float acc[32];
#pragma unroll
        for (int rr = 0; rr < 32; ++rr) acc[rr] = 0.f;
        gemm_k<32>(&sH[0][0], 128, rh * 32, sW, 128, c, acc);
        float b1 = ldf(aaB1, c, isbf);
#pragma unroll
        for (int rr = 0; rr < 32; ++rr) {
            float v = acc[rr] + b1;
            g_A0[(size_t)(b * 64 + rh * 32 + rr) * 128 + c] = v > 0.f ? v : 0.f;
        }
    }
    __syncthreads();
    for (int idx = t; idx < 150 * 128; idx += 256) sW[idx] = ldw(apW0, idx, isbf);
    __syncthreads();
    {
        float acc[32];
#pragma unroll
        for (int rr = 0; rr < 32; ++rr) acc[rr] = 0.f;
        gemm_k<32>(&sX[0][0], 76, rh * 32, sW, FA_, c, acc);             // T
#pragma unroll
        for (int rr = 0; rr < 32; ++rr)
            g_TB[(size_t)(b * 64 + rh * 32 + rr) * 256 + c] = acc[rr];
#pragma unroll
        for (int rr = 0; rr < 32; ++rr) acc[rr] = 0.f;
        gemm_k<32>(&sX[0][0], 76, rh * 32, sW + FA_ * 128, FA_, c, acc); // Bo
#pragma unroll
        for (int rr = 0; rr < 32; ++rr)
            g_TB[(size_t)(b * 64 + rh * 32 + rr) * 256 + 128 + c] = acc[rr];
    }
}

// ---------------- Kernel 2: PairToAtom (mlp2 + sum over j) ----------------
__global__ __launch_bounds__(256) void p2a_sum(
    const void* __restrict__ pairx,
    const void* __restrict__ W0, const void* __restrict__ B0,
    const void* __restrict__ W1, const void* __restrict__ B1) {
    __shared__ u16 sP[64][16];
    __shared__ u16 sW[128 * 128];
    __shared__ u16 sH[64][128];
    __shared__ float sSum[2][128];
    const bool isbf = g_isbf != 0;
    const int t = threadIdx.x;
    const int bx = blockIdx.x;
    for (int idx = t; idx < 64 * FP_; idx += 256) {
        int r = idx / FP_, k = idx - r * FP_;
        sP[r][k] = ldw(pairx, ((size_t)bx * 64 + r) * FP_ + k, isbf);
    }
    for (int idx = t; idx < FP_ * 128; idx += 256) sW[idx] = ldw(W0, idx, isbf);
    __syncthreads();
    const int c = t & 127, rh = t >> 7;
    {
        float acc[32];
#pragma unroll
        for (int rr = 0; rr < 32; ++rr) acc[rr] = 0.f;
        gemm_k<32>(&sP[0][0], 16, rh * 32, sW, FP_, c, acc);
        float b0 = ldf(B0, c, isbf);
#pragma unroll
        for (int rr = 0; rr < 32; ++rr) {
            float v = acc[rr] + b0;
            sH[rh * 32 + rr][c] = f2bf(v > 0.f ? v : 0.f);
        }
    }
    __syncthreads();
    for (int idx = t; idx < 128 * 128; idx += 256) sW[idx] = ldw(W1, idx, isbf);
    __syncthreads();
    {
        float acc[32];
#pragma unroll
        for (int rr = 0; rr < 32; ++rr) acc[rr] = 0.f;
        gemm_k<32>(&sH[0][0], 128, rh * 32, sW, 128, c, acc);
        float b1 = ldf(B1, c, isbf);
        float csum = 0.f;
#pragma unroll
        for (int rr = 0; rr < 32; ++rr) {
            float v = acc[rr] + b1;
            csum += (v > 0.f ? v : 0.f);
        }
        sSum[rh][c] = csum;
    }
    __syncthreads();
    if (t < 128) g_A1[(size_t)bx * 128 + t] = sSum[0][t] + sSum[1][t];
}

// ---------------- Kernel 3: atom_layer (fp32 A operands) ----------------
__global__ __launch_bounds__(256) void atom_layer(
    const void* __restrict__ W0, const void* __restrict__ B0,
    const void* __restrict__ W1, const void* __restrict__ B1,
    void* __restrict__ out) {
    __shared__ float sXf[32][128];
    __shared__ u16 sW[128 * 128];
    __shared__ u16 sH[32][128];
    const bool isbf = g_isbf != 0;
    const int t = threadIdx.x;
    const int r0g = blockIdx.x * 32;
    const int c = t & 127, rh = t >> 7;
    float hacc[16];
#pragma unroll
    for (int rr = 0; rr < 16; ++rr) hacc[rr] = 0.f;
    for (int idx = t; idx < 32 * 128; idx += 256) {
        int r = idx >> 7, cc = idx & 127;
        sXf[r][cc] = g_A0[(size_t)(r0g + r) * 128 + cc];
    }
    for (int idx = t; idx < 128 * 128; idx += 256) sW[idx] = ldw(W0, idx, isbf);
    __syncthreads();
    gemm_kf<16>(&sXf[0][0], 128, rh * 16, sW, 128, c, hacc);
    __syncthreads();
    for (int idx = t; idx < 32 * 128; idx += 256) {
        int r = idx >> 7, cc = idx & 127;
        sXf[r][cc] = g_A1[(size_t)(r0g + r) * 128 + cc];
    }
    for (int idx = t; idx < 128 * 128; idx += 256) sW[idx] = ldw(W0, 128 * 128 + idx, isbf);
    __syncthreads();
    gemm_kf<16>(&sXf[0][0], 128, rh * 16, sW, 128, c, hacc);
    {
        float b0 = ldf(B0, c, isbf);
#pragma unroll
        for (int rr = 0; rr < 16; ++rr) {
            float v = hacc[rr] + b0;
            sH[rh * 16 + rr][c] = f2bf(v > 0.f ? v : 0.f);
        }
    }
    __syncthreads();
    for (int idx = t; idx < 128 * 128; idx += 256) sW[idx] = ldw(W1, idx, isbf);
    __syncthreads();
    {
        float acc[16];
#pragma unroll
        for (int rr = 0; rr < 16; ++rr) acc[rr] = 0.f;
        gemm_k<16>(&sH[0][0], 128, rh * 16, sW, 128, c, acc);
        float b1 = ldf(B1, c, isbf);
#pragma unroll
        for (int rr = 0; rr < 16; ++rr) {
            float v = acc[rr] + b1;                 // relu(relu(x)) == relu(x)
            stout(out, (size_t)(r0g + rh * 16 + rr) * 128 + c, v > 0.f ? v : 0.f, isbf);
        }
    }
}

// ---------------- Kernel 4: fused pair branch ----------------
__global__ __launch_bounds__(256) void pair_fused(
    const void* __restrict__ pairx,
    const void* __restrict__ apB0, const void* __restrict__ apW1, const void* __restrict__ apB1,
    const void* __restrict__ ppW0, const void* __restrict__ ppB0,
    const void* __restrict__ ppW1, const void* __restrict__ ppB1,
    const void* __restrict__ plW0, const void* __restrict__ plB0,
    const void* __restrict__ plW1, const void* __restrict__ plB1,
    void* __restrict__ out) {
    __shared__ u16 sW[128 * 128];
    __shared__ u16 sH0[32][128];
    __shared__ u16 sH1[32][128];
    __shared__ u16 sP0[32][128];
    __shared__ u16 sW0s[FP_ * 128];
    __shared__ u16 sPr[32][16];
    const bool isbf = g_isbf != 0;
    const int t = threadIdx.x;
    const int bx = blockIdx.x;
    const int b = bx >> 7, i = (bx >> 1) & 63, half = bx & 1;
    const int jbase = half * 32;
    const int trow = b * 64;
    const size_t prow0 = (size_t)b * 4096 + i * 64 + jbase;

    for (int idx = t; idx < 32 * FP_; idx += 256) {
        int r = idx / FP_, k = idx - r * FP_;
        sPr[r][k] = ldw(pairx, (prow0 + r) * FP_ + k, isbf);
    }
    // H0[j][c] = relu(T[i]+Bo[j]+b0);  H1[j][c] = relu(T[j]+Bo[i]+b0)
    for (int idx = t; idx < 32 * 128; idx += 256) {
        int j = idx >> 7, cc = idx & 127;
        float bb  = ldf(apB0, cc, isbf);
        float Ti  = g_TB[(size_t)(trow + i) * 256 + cc];
        float Boi = g_TB[(size_t)(trow + i) * 256 + 128 + cc];
        float Tj  = g_TB[(size_t)(trow + jbase + j) * 256 + cc];
        float Boj = g_TB[(size_t)(trow + jbase + j) * 256 + 128 + cc];
        float h0 = Ti + Boj + bb;
        float h1 = Tj + Boi + bb;
        sH0[j][cc] = f2bf(h0 > 0.f ? h0 : 0.f);
        sH1[j][cc] = f2bf(h1 > 0.f ? h1 : 0.f);
    }
    for (int idx = t; idx < 128 * 128; idx += 256) sW[idx] = ldw(apW1, idx, isbf);
    __syncthreads();

    const int c = t & 127, rh = t >> 7;
    const float b1a = ldf(apB1, c, isbf);
    float acc[16];
#pragma unroll
    for (int rr = 0; rr < 16; ++rr) acc[rr] = 0.f;
    gemm_k<16>(&sH0[0][0], 128, rh * 16, sW, 128, c, acc);
#pragma unroll
    for (int rr = 0; rr < 16; ++rr) {
        float v = acc[rr] + b1a;
        sP0[rh * 16 + rr][c] = f2bf(v > 0.f ? v : 0.f);
    }
#pragma unroll
    for (int rr = 0; rr < 16; ++rr) acc[rr] = 0.f;
    gemm_k<16>(&sH1[0][0], 128, rh * 16, sW, 128, c, acc);
#pragma unroll
    for (int rr = 0; rr < 16; ++rr) {
        float v = acc[rr] + b1a;
        float p = bf2f(sP0[rh * 16 + rr][c]) + (v > 0.f ? v : 0.f);
        sP0[rh * 16 + rr][c] = f2bf(p);
    }
    __syncthreads();
    for (int idx = t; idx < 128 * 128; idx += 256) sW[idx] = ldw(plW0, idx, isbf);
    __syncthreads();
    float hacc[16];
#pragma unroll
    for (int rr = 0; rr < 16; ++rr) hacc[rr] = 0.f;
    gemm_k<16>(&sP0[0][0], 128, rh * 16, sW, 128, c, hacc);
    __syncthreads();
    for (int idx = t; idx < FP_ * 128; idx += 256) sW0s[idx] = ldw(ppW0, idx, isbf);
    for (int idx = t; idx < 128 * 128; idx += 256) sW[idx] = ldw(ppW1, idx, isbf);
    __syncthreads();
    {
        float b0p = ldf(ppB0, c, isbf);
#pragma unroll
        for (int rr = 0; rr < 16; ++rr) acc[rr] = 0.f;
        gemm_k<16>(&sPr[0][0], 16, rh * 16, sW0s, FP_, c, acc);
#pragma unroll
        for (int rr = 0; rr < 16; ++rr) {
            float v = acc[rr] + b0p;
            sH0[rh * 16 + rr][c] = f2bf(v > 0.f ? v : 0.f);
        }
    }
    __syncthreads();
    {
        float b1p = ldf(ppB1, c, isbf);
#pragma unroll
        for (int rr = 0; rr < 16; ++rr) acc[rr] = 0.f;
        gemm_k<16>(&sH0[0][0], 128, rh * 16, sW, 128, c, acc);
#pragma unroll
        for (int rr = 0; rr < 16; ++rr) {
            float v = acc[rr] + b1p;
            sH1[rh * 16 + rr][c] = f2bf(v > 0.f ? v : 0.f);
        }
    }
    __syncthreads();
    for (int idx = t; idx < 128 * 128; idx += 256) sW[idx] = ldw(plW0, 128 * 128 + idx, isbf);
    __syncthreads();
    gemm_k<16>(&sH1[0][0], 128, rh * 16, sW, 128, c, hacc);
    {
        float b0l = ldf(plB0, c, isbf);
#pragma unroll
        for (int rr = 0; rr < 16; ++rr) {
            float v = hacc[rr] + b0l;
            sP0[rh * 16 + rr][c] = f2bf(v > 0.f ? v : 0.f);
        }
    }
    __syncthreads();
    for (int idx = t; idx < 128 * 128; idx += 256) sW[idx] = ldw(plW1, idx, isbf);
    __syncthreads();
    {
        float b1l = ldf(plB1, c, isbf);
#pragma unroll
        for (int rr = 0; rr < 16; ++rr) acc[rr] = 0.f;
        gemm_k<16>(&sP0[0][0], 128, rh * 16, sW, 128, c, acc);
        const size_t NA = (size_t)B_ * N_ * C_;
#pragma unroll
        for (int rr = 0; rr < 16; ++rr) {
            float v = acc[rr] + b1l;
            stout(out, NA + (prow0 + rh * 16 + rr) * 128 + c, v > 0.f ? v : 0.f, isbf);
        }
    }
}

extern "C" void kernel_launch(void* const* d_in, const int* in_sizes, int n_in,
                              void* d_out, int out_size, void* d_ws, size_t ws_size,
                              hipStream_t stream) {
    const void* atom  = d_in[0];
    const void* pairx = d_in[1];
    const void* aaW0 = d_in[2];  const void* aaB0 = d_in[3];
    const void* aaW1 = d_in[4];  const void* aaB1 = d_in[5];
    const void* paW0 = d_in[6];  const void* paB0 = d_in[7];
    const void* paW1 = d_in[8];  const void* paB1 = d_in[9];
    const void* alW0 = d_in[10]; const void* alB0 = d_in[11];
    const void* alW1 = d_in[12]; const void* alB1 = d_in[13];
    const void* apW0 = d_in[14]; const void* apB0 = d_in[15];
    const void* apW1 = d_in[16]; const void* apB1 = d_in[17];
    const void* ppW0 = d_in[18]; const void* ppB0 = d_in[19];
    const void* ppW1 = d_in[20]; const void* ppB1 = d_in[21];
    const void* plW0 = d_in[22]; const void* plB0 = d_in[23];
    const void* plW1 = d_in[24]; const void* plB1 = d_in[25];
    (void)d_ws; (void)ws_size; (void)in_sizes; (void)n_in; (void)out_size;

    detect_k<<<1, 64, 0, stream>>>(atom);
    atom_pre<<<64, 256, 0, stream>>>(atom, aaW0, aaB0, aaW1, aaB1, apW0);
    p2a_sum<<<4096, 256, 0, stream>>>(pairx, paW0, paB0, paW1, paB1);
    atom_layer<<<128, 256, 0, stream>>>(alW0, alB0, alW1, alB1, d_out);
    pair_fused<<<8192, 256, 0, stream>>>(pairx,
                                         apB0, apW1, apB1,
                                         ppW0, ppB0, ppW1, ppB1,
                                         plW0, plB0, plW1, plB1,
                                         d_out);
}

// Round 4
// 347.982 us; speedup vs baseline: 8.8149x; 8.8149x over previous
//
#include <hip/hip_runtime.h>
#include <hip/hip_bf16.h>

typedef unsigned short u16;
typedef unsigned int u32;
typedef __attribute__((ext_vector_type(8))) __bf16 bf16x8;
typedef __attribute__((ext_vector_type(4))) float f32x4;

#define B_ 64
#define N_ 64
#define FA_ 75
#define FP_ 14
#define C_ 128

// ---- static device scratch (fully rewritten every call) ----
__device__ float g_A0[4096 * 128];   // a0 branch, fp32 [row][feat]
__device__ float g_A1[4096 * 128];   // p2a-summed branch, fp32
__device__ float g_TB[4096 * 256];   // [T | Bo] per atom row, fp32
__device__ u16   g_Wf[208896];       // all weights in A-fragment layout (bf16)
__device__ int   g_isbf;             // 1=bf16 inputs, 0=fp32 inputs

// frag-weight offsets (u16 elements); layout slot = ((mt*KS+ks)*64+lane)*8+j
#define OFF_AA0   0        // aaW0   K=75->96  KS3
#define OFF_AA1   12288    // aaW1   K=128     KS4
#define OFF_APT   28672    // apW0 top (rows 0..74)   KS3
#define OFF_APB   40960    // apW0 bot (rows 75..149) KS3
#define OFF_PA0   53248    // paW0   K=14->32  KS1
#define OFF_PA1   57344    // paW1   KS4
#define OFF_AL0   73728    // alW0   K=256     KS8
#define OFF_AL1   106496   // alW1   KS4
#define OFF_AP1   122880   // apW1   KS4
#define OFF_PP0   139264   // ppW0   K=14->32  KS1
#define OFF_PP1   143360   // ppW1   KS4
#define OFF_PL0T  159744   // plW0 rows 0..127   KS4
#define OFF_PL0B  176128   // plW0 rows 128..255 KS4
#define OFF_PL1   192512   // plW1   KS4

__device__ __forceinline__ float bf2f(u16 a) {
    union { u32 u; float f; } v; v.u = ((u32)a) << 16; return v.f;
}
__device__ __forceinline__ u16 f2bf(float f) {
    union { float f; u32 u; } v; v.f = f;
    u32 r = v.u + 0x7fffu + ((v.u >> 16) & 1u);   // RNE
    return (u16)(r >> 16);
}
__device__ __forceinline__ u16 ldw(const void* p, size_t i, bool isbf) {
    if (isbf) return ((const u16*)p)[i];
    return f2bf(((const float*)p)[i]);
}
__device__ __forceinline__ float ldf(const void* p, size_t i, bool isbf) {
    if (isbf) return bf2f(((const u16*)p)[i]);
    return ((const float*)p)[i];
}

// ---------------- dtype detect ----------------
__global__ void detect_k(const void* __restrict__ atom) {
    if (threadIdx.x == 0) {
        const u32* a = (const u32*)atom;
        int sane = 0;
        for (int w = 0; w < 64; ++w) {
            u32 ex = (a[w] >> 7) & 0xffu;          // exponent of LOW bf16 half
            sane += (ex >= 113u && ex <= 133u) ? 1 : 0;
        }
        g_isbf = (sane >= 32) ? 1 : 0;
    }
}

// ---------------- weight prep: global [K][128] -> A-frag layout ----------------
__global__ __launch_bounds__(256) void prep_w(
    const void* aaW0, const void* aaW1, const void* apW0,
    const void* paW0, const void* paW1, const void* alW0, const void* alW1,
    const void* apW1, const void* ppW0, const void* ppW1,
    const void* plW0, const void* plW1) {
    const void* srcs[14] = {aaW0, aaW1, apW0, apW0, paW0, paW1, alW0, alW1,
                            apW1, ppW0, ppW1, plW0, plW0, plW1};
    const int Ktab[14]  = {75, 128, 75, 75, 14, 128, 256, 128, 128, 14, 128, 128, 128, 128};
    const int KStab[14] = {3, 4, 3, 3, 1, 4, 8, 4, 4, 1, 4, 4, 4, 4};
    const int rofft[14] = {0, 0, 0, 75, 0, 0, 0, 0, 0, 0, 0, 0, 128, 0};
    const int baset[14] = {OFF_AA0, OFF_AA1, OFF_APT, OFF_APB, OFF_PA0, OFF_PA1,
                           OFF_AL0, OFF_AL1, OFF_AP1, OFF_PP0, OFF_PP1,
                           OFF_PL0T, OFF_PL0B, OFF_PL1};
    int gid = blockIdx.x * 256 + threadIdx.x;
    int j = 0, s = gid;
    while (j < 14 && s >= KStab[j] * 512) { s -= KStab[j] * 512; ++j; }
    if (j >= 14) return;
    const bool isbf = g_isbf != 0;
    int lane = s & 63, rest = s >> 6;
    int ks = rest % KStab[j], mt = rest / KStab[j];
    int m = mt * 16 + (lane & 15), q = lane >> 4;
    union { u16 h[8]; uint4 u4; } pk;
#pragma unroll
    for (int jj = 0; jj < 8; ++jj) {
        int k = ks * 32 + q * 8 + jj;
        pk.h[jj] = (k < Ktab[j]) ? ldw(srcs[j], (size_t)(rofft[j] + k) * 128 + m, isbf) : (u16)0;
    }
    *(uint4*)&g_Wf[(size_t)baset[j] + (size_t)s * 8] = pk.u4;
}

// ---------------- MFMA GEMM core ----------------
// D[m][n] = sum_k Wt[m][k] * X[n][k]  (i.e. (X@W)[n][m]); wave does mt0,mt0+1 x NT n-tiles.
// wf: global frag weights; bF: LDS activation frags [nt][KS][64][8].
template<int KS, int NT>
__device__ __forceinline__ void gemm2(const u16* __restrict__ wf,
                                      const u16* __restrict__ bF,
                                      int mt0, int lane, f32x4 (&acc)[2][NT]) {
#pragma unroll
    for (int ks = 0; ks < KS; ++ks) {
        bf16x8 a0 = *(const bf16x8*)(wf + (((mt0    ) * KS + ks) * 64 + lane) * 8);
        bf16x8 a1 = *(const bf16x8*)(wf + (((mt0 + 1) * KS + ks) * 64 + lane) * 8);
#pragma unroll
        for (int nt = 0; nt < NT; ++nt) {
            bf16x8 b = *(const bf16x8*)(bF + ((nt * KS + ks) * 64 + lane) * 8);
            acc[0][nt] = __builtin_amdgcn_mfma_f32_16x16x32_bf16(a0, b, acc[0][nt], 0, 0, 0);
            acc[1][nt] = __builtin_amdgcn_mfma_f32_16x16x32_bf16(a1, b, acc[1][nt], 0, 0, 0);
        }
    }
}

// Store one C-frag (rows m=mt*16+quad*4+r, col n=nt*16+c) as next-layer B-frags.
// slot lane' = c + 16*((m>>3)&3), j = m&7 -> reg r maps to contiguous j -> one b64 write.
__device__ __forceinline__ void frag_store(u16* dstF, int KSd, int nt, int mt, int lane, f32x4 v) {
    int c = lane & 15, quad = lane >> 4;
    int lp = c + 16 * ((2 * mt + (quad >> 1)) & 3);
    int ks = mt >> 1;
    u16* p = dstF + (((nt * KSd + ks) * 64 + lp) * 8 + (quad & 1) * 4);
    union { u16 h[4]; uint2 u; } pk;
    pk.h[0] = f2bf(v[0]); pk.h[1] = f2bf(v[1]); pk.h[2] = f2bf(v[2]); pk.h[3] = f2bf(v[3]);
    *(uint2*)p = pk.u;
}

__device__ __forceinline__ void store_out4(void* outp, size_t elem, f32x4 v, bool isbf) {
    if (isbf) {
        union { u16 h[4]; uint2 u; } pk;
        pk.h[0] = f2bf(v[0]); pk.h[1] = f2bf(v[1]); pk.h[2] = f2bf(v[2]); pk.h[3] = f2bf(v[3]);
        *(uint2*)((u16*)outp + elem) = pk.u;
    } else {
        *(f32x4*)((float*)outp + elem) = v;
    }
}

#define EPI_RELU_STORE(ACC, SB, DST, NTN) do {                                   \
    int quad_ = lane >> 4;                                                       \
    _Pragma("unroll") for (int ii = 0; ii < 2; ++ii) {                           \
        int mt_ = mt0 + ii;                                                      \
        f32x4 bb_ = *(const f32x4*)&SB[mt_ * 16 + quad_ * 4];                    \
        _Pragma("unroll") for (int nt_ = 0; nt_ < NTN; ++nt_) {                  \
            f32x4 v_;                                                            \
            _Pragma("unroll") for (int r_ = 0; r_ < 4; ++r_) {                   \
                float x_ = ACC[ii][nt_][r_] + bb_[r_];                           \
                v_[r_] = x_ > 0.f ? x_ : 0.f;                                    \
            }                                                                    \
            frag_store(DST, 4, nt_, mt_, lane, v_);                              \
        }                                                                        \
    }                                                                            \
} while (0)

// ---------------- Kernel: atom branch pre-work (per b; 64 rows, M=128, 4 nt) --------
__global__ __launch_bounds__(256) void atom_pre(
    const void* __restrict__ atom,
    const void* __restrict__ aaB0, const void* __restrict__ aaB1) {
    __shared__ __align__(16) u16 sXF[4 * 3 * 64 * 8];   // atom frags Kp=96, 12KB
    __shared__ __align__(16) u16 sHF[4 * 4 * 64 * 8];   // hidden frags, 16KB
    __shared__ __align__(16) float sB0[128], sB1[128];
    const bool isbf = g_isbf != 0;
    const int t = threadIdx.x, lane = t & 63, w = t >> 6;
    const int b = blockIdx.x;
    if (t < 128) { sB0[t] = ldf(aaB0, t, isbf); sB1[t] = ldf(aaB1, t, isbf); }
    for (int s = t; s < 4 * 3 * 64; s += 256) {
        int lane_s = s & 63, rest = s >> 6;
        int ks = rest % 3, nt = rest / 3;
        int n = nt * 16 + (lane_s & 15), q = lane_s >> 4;
        union { u16 h[8]; uint4 u4; } pk;
#pragma unroll
        for (int j = 0; j < 8; ++j) {
            int k = ks * 32 + q * 8 + j;
            pk.h[j] = (k < FA_) ? ldw(atom, (size_t)(b * 64 + n) * FA_ + k, isbf) : (u16)0;
        }
        *(uint4*)&sXF[s * 8] = pk.u4;
    }
    __syncthreads();
    const int mt0 = 2 * w;
    // L1: H = relu(X@aaW0 + b0)
    {
        f32x4 acc[2][4];
#pragma unroll
        for (int ii = 0; ii < 2; ++ii)
#pragma unroll
            for (int nt = 0; nt < 4; ++nt) acc[ii][nt] = (f32x4){0.f, 0.f, 0.f, 0.f};
        gemm2<3, 4>(g_Wf + OFF_AA0, sXF, mt0, lane, acc);
        EPI_RELU_STORE(acc, sB0, sHF, 4);
    }
    __syncthreads();
    // L2: g_A0 = relu(H@aaW1 + b1)   (fp32, [row][feat])
    {
        f32x4 acc[2][4];
#pragma unroll
        for (int ii = 0; ii < 2; ++ii)
#pragma unroll
            for (int nt = 0; nt < 4; ++nt) acc[ii][nt] = (f32x4){0.f, 0.f, 0.f, 0.f};
        gemm2<4, 4>(g_Wf + OFF_AA1, sHF, mt0, lane, acc);
        int c = lane & 15, quad = lane >> 4;
#pragma unroll
        for (int ii = 0; ii < 2; ++ii) {
            int mt = mt0 + ii;
            f32x4 bb = *(const f32x4*)&sB1[mt * 16 + quad * 4];
#pragma unroll
            for (int nt = 0; nt < 4; ++nt) {
                f32x4 v;
#pragma unroll
                for (int r = 0; r < 4; ++r) { float x = acc[ii][nt][r] + bb[r]; v[r] = x > 0.f ? x : 0.f; }
                *(f32x4*)&g_A0[(size_t)(b * 64 + nt * 16 + c) * 128 + mt * 16 + quad * 4] = v;
            }
        }
    }
    // T / Bo: plain GEMMs over sXF (still intact), no bias/relu -> g_TB fp32
    {
        f32x4 accT[2][4], accB[2][4];
#pragma unroll
        for (int ii = 0; ii < 2; ++ii)
#pragma unroll
            for (int nt = 0; nt < 4; ++nt) { accT[ii][nt] = (f32x4){0.f,0.f,0.f,0.f}; accB[ii][nt] = (f32x4){0.f,0.f,0.f,0.f}; }
        gemm2<3, 4>(g_Wf + OFF_APT, sXF, mt0, lane, accT);
        gemm2<3, 4>(g_Wf + OFF_APB, sXF, mt0, lane, accB);
        int c = lane & 15, quad = lane >> 4;
#pragma unroll
        for (int ii = 0; ii < 2; ++ii) {
            int mt = mt0 + ii;
#pragma unroll
            for (int nt = 0; nt < 4; ++nt) {
                size_t row = (size_t)(b * 64 + nt * 16 + c);
                *(f32x4*)&g_TB[row * 256 + mt * 16 + quad * 4] = accT[ii][nt];
                *(f32x4*)&g_TB[row * 256 + 128 + mt * 16 + quad * 4] = accB[ii][nt];
            }
        }
    }
}

// ---------------- Kernel: PairToAtom (per (b,i); 64 rows; sum over rows) ----------
__global__ __launch_bounds__(256) void p2a_sum(
    const void* __restrict__ pairx,
    const void* __restrict__ paB0, const void* __restrict__ paB1) {
    __shared__ __align__(16) u16 sPF[4 * 1 * 64 * 8];   // pair frags Kp=32, 4KB
    __shared__ __align__(16) u16 sHF[4 * 4 * 64 * 8];   // 16KB
    __shared__ __align__(16) float sB0[128], sB1[128];
    const bool isbf = g_isbf != 0;
    const int t = threadIdx.x, lane = t & 63, w = t >> 6;
    const int bx = blockIdx.x;
    const size_t rbase = (size_t)bx * 64;
    if (t < 128) { sB0[t] = ldf(paB0, t, isbf); sB1[t] = ldf(paB1, t, isbf); }
    if (t < 256) {
        int s = t;
        int lane_s = s & 63, nt = s >> 6;
        int n = nt * 16 + (lane_s & 15), q = lane_s >> 4;
        union { u16 h[8]; uint4 u4; } pk;
#pragma unroll
        for (int j = 0; j < 8; ++j) {
            int k = q * 8 + j;
            pk.h[j] = (k < FP_) ? ldw(pairx, (rbase + n) * FP_ + k, isbf) : (u16)0;
        }
        *(uint4*)&sPF[s * 8] = pk.u4;
    }
    __syncthreads();
    const int mt0 = 2 * w;
    {
        f32x4 acc[2][4];
#pragma unroll
        for (int ii = 0; ii < 2; ++ii)
#pragma unroll
            for (int nt = 0; nt < 4; ++nt) acc[ii][nt] = (f32x4){0.f, 0.f, 0.f, 0.f};
        gemm2<1, 4>(g_Wf + OFF_PA0, sPF, mt0, lane, acc);
        EPI_RELU_STORE(acc, sB0, sHF, 4);
    }
    __syncthreads();
    {
        f32x4 acc[2][4];
#pragma unroll
        for (int ii = 0; ii < 2; ++ii)
#pragma unroll
            for (int nt = 0; nt < 4; ++nt) acc[ii][nt] = (f32x4){0.f, 0.f, 0.f, 0.f};
        gemm2<4, 4>(g_Wf + OFF_PA1, sHF, mt0, lane, acc);
        int quad = lane >> 4;
#pragma unroll
        for (int ii = 0; ii < 2; ++ii) {
            int mt = mt0 + ii;
            f32x4 bb = *(const f32x4*)&sB1[mt * 16 + quad * 4];
            f32x4 ssum = (f32x4){0.f, 0.f, 0.f, 0.f};
#pragma unroll
            for (int nt = 0; nt < 4; ++nt)
#pragma unroll
                for (int r = 0; r < 4; ++r) {
                    float x = acc[ii][nt][r] + bb[r];
                    ssum[r] += (x > 0.f ? x : 0.f);
                }
#pragma unroll
            for (int m = 1; m < 16; m <<= 1)
#pragma unroll
                for (int r = 0; r < 4; ++r) ssum[r] += __shfl_xor(ssum[r], m, 64);
            if ((lane & 15) == 0)
                *(f32x4*)&g_A1[(size_t)bx * 128 + mt * 16 + quad * 4] = ssum;
        }
    }
}

// ---------------- Kernel: atom_layer (32 rows/block, K=256 then 128) --------------
__global__ __launch_bounds__(256) void atom_layer(
    const void* __restrict__ alB0, const void* __restrict__ alB1,
    void* __restrict__ out) {
    __shared__ __align__(16) u16 sXF[2 * 8 * 64 * 8];   // 16KB (K=256)
    __shared__ __align__(16) u16 sHF[2 * 4 * 64 * 8];   // 8KB
    __shared__ __align__(16) float sB0[128], sB1[128];
    const bool isbf = g_isbf != 0;
    const int t = threadIdx.x, lane = t & 63, w = t >> 6;
    const int r0g = blockIdx.x * 32;
    if (t < 128) { sB0[t] = ldf(alB0, t, isbf); sB1[t] = ldf(alB1, t, isbf); }
    for (int s = t; s < 2 * 8 * 64; s += 256) {
        int lane_s = s & 63, rest = s >> 6;
        int ks = rest % 8, nt = rest / 8;
        int n = nt * 16 + (lane_s & 15), q = lane_s >> 4;
        union { u16 h[8]; uint4 u4; } pk;
#pragma unroll
        for (int j = 0; j < 8; ++j) {
            int k = ks * 32 + q * 8 + j;
            float v = (k < 128) ? g_A0[(size_t)(r0g + n) * 128 + k]
                                : g_A1[(size_t)(r0g + n) * 128 + (k - 128)];
            pk.h[j] = f2bf(v);
        }
        *(uint4*)&sXF[s * 8] = pk.u4;
    }
    __syncthreads();
    const int mt0 = 2 * w;
    {
        f32x4 acc[2][2];
#pragma unroll
        for (int ii = 0; ii < 2; ++ii)
#pragma unroll
            for (int nt = 0; nt < 2; ++nt) acc[ii][nt] = (f32x4){0.f, 0.f, 0.f, 0.f};
        gemm2<8, 2>(g_Wf + OFF_AL0, sXF, mt0, lane, acc);
        EPI_RELU_STORE(acc, sB0, sHF, 2);
    }
    __syncthreads();
    {
        f32x4 acc[2][2];
#pragma unroll
        for (int ii = 0; ii < 2; ++ii)
#pragma unroll
            for (int nt = 0; nt < 2; ++nt) acc[ii][nt] = (f32x4){0.f, 0.f, 0.f, 0.f};
        gemm2<4, 2>(g_Wf + OFF_AL1, sHF, mt0, lane, acc);
        int c = lane & 15, quad = lane >> 4;
#pragma unroll
        for (int ii = 0; ii < 2; ++ii) {
            int mt = mt0 + ii;
            f32x4 bb = *(const f32x4*)&sB1[mt * 16 + quad * 4];
#pragma unroll
            for (int nt = 0; nt < 2; ++nt) {
                f32x4 v;
#pragma unroll
                for (int r = 0; r < 4; ++r) { float x = acc[ii][nt][r] + bb[r]; v[r] = x > 0.f ? x : 0.f; }
                store_out4(out, (size_t)(r0g + nt * 16 + c) * 128 + mt * 16 + quad * 4, v, isbf);
            }
        }
    }
}

// ---------------- Kernel: fused pair branch (32 rows/block) -----------------------
__global__ __launch_bounds__(256) void pair_fused(
    const void* __restrict__ pairx,
    const void* __restrict__ apB0, const void* __restrict__ apB1,
    const void* __restrict__ ppB0, const void* __restrict__ ppB1,
    const void* __restrict__ plB0, const void* __restrict__ plB1,
    void* __restrict__ out) {
    __shared__ __align__(16) u16 sPrF[2 * 1 * 64 * 8];  // 2KB pair_x pad-32 frags
    __shared__ __align__(16) u16 sH0F[2 * 4 * 64 * 8];  // 8KB (H0 -> P1)
    __shared__ __align__(16) u16 sH1F[2 * 4 * 64 * 8];  // 8KB (H1 -> Hl)
    __shared__ __align__(16) u16 sP0F[2 * 4 * 64 * 8];  // 8KB
    __shared__ __align__(16) u16 sHpF[2 * 4 * 64 * 8];  // 8KB
    __shared__ __align__(16) float sBap0[128], sBap1[128], sBpp0[128],
                                   sBpp1[128], sBpl0[128], sBpl1[128];
    const bool isbf = g_isbf != 0;
    const int t = threadIdx.x, lane = t & 63, w = t >> 6;
    const int bx = blockIdx.x;
    const int b = bx >> 7, i = (bx >> 1) & 63, half = bx & 1;
    const int jbase = half * 32, trow = b * 64;
    const size_t prow0 = (size_t)b * 4096 + i * 64 + jbase;

    // phase A: biases + padded pair_x frags
    if (t < 128) {
        sBap0[t] = ldf(apB0, t, isbf); sBap1[t] = ldf(apB1, t, isbf);
        sBpp0[t] = ldf(ppB0, t, isbf); sBpp1[t] = ldf(ppB1, t, isbf);
        sBpl0[t] = ldf(plB0, t, isbf); sBpl1[t] = ldf(plB1, t, isbf);
    }
    if (t < 128) {
        int s = t;
        int lane_s = s & 63, nt = s >> 6;
        int n = nt * 16 + (lane_s & 15), q = lane_s >> 4;
        union { u16 h[8]; uint4 u4; } pk;
#pragma unroll
        for (int j = 0; j < 8; ++j) {
            int k = q * 8 + j;
            pk.h[j] = (k < FP_) ? ldw(pairx, (prow0 + n) * FP_ + k, isbf) : (u16)0;
        }
        *(uint4*)&sPrF[s * 8] = pk.u4;
    }
    __syncthreads();
    // phase B: H0/H1 = relu(T_i + Bo_j + b0) / relu(T_j + Bo_i + b0), straight to frags
    for (int sid = t; sid < 1024; sid += 256) {
        int bufid = sid >> 9;
        int s = sid & 511;
        int lane_s = s & 63, rest = s >> 6;
        int ks = rest & 3, nt = rest >> 2;
        int n = nt * 16 + (lane_s & 15), q = lane_s >> 4;
        int k0 = ks * 32 + q * 8;
        const float* Ti = &g_TB[(size_t)(trow + i) * 256];
        const float* Bj = &g_TB[(size_t)(trow + jbase + n) * 256];
        union { u16 h[8]; uint4 u4; } pk;
#pragma unroll
        for (int j = 0; j < 8; ++j) {
            int k = k0 + j;
            float v = (bufid == 0) ? (Ti[k] + Bj[128 + k] + sBap0[k])
                                   : (Bj[k] + Ti[128 + k] + sBap0[k]);
            pk.h[j] = f2bf(v > 0.f ? v : 0.f);
        }
        *(uint4*)&(bufid == 0 ? sH0F : sH1F)[s * 8] = pk.u4;
    }
    __syncthreads();
    const int mt0 = 2 * w;
    // L2: P0 = relu(H0@apW1+b1) + relu(H1@apW1+b1)
    {
        f32x4 aA[2][2], aB[2][2];
#pragma unroll
        for (int ii = 0; ii < 2; ++ii)
#pragma unroll
            for (int nt = 0; nt < 2; ++nt) { aA[ii][nt] = (f32x4){0.f,0.f,0.f,0.f}; aB[ii][nt] = (f32x4){0.f,0.f,0.f,0.f}; }
        gemm2<4, 2>(g_Wf + OFF_AP1, sH0F, mt0, lane, aA);
        gemm2<4, 2>(g_Wf + OFF_AP1, sH1F, mt0, lane, aB);
        int quad = lane >> 4;
#pragma unroll
        for (int ii = 0; ii < 2; ++ii) {
            int mt = mt0 + ii;
            f32x4 bb = *(const f32x4*)&sBap1[mt * 16 + quad * 4];
#pragma unroll
            for (int nt = 0; nt < 2; ++nt) {
                f32x4 v;
#pragma unroll
                for (int r = 0; r < 4; ++r) {
                    float x = aA[ii][nt][r] + bb[r];
                    float y = aB[ii][nt][r] + bb[r];
                    v[r] = (x > 0.f ? x : 0.f) + (y > 0.f ? y : 0.f);
                }
                frag_store(sP0F, 4, nt, mt, lane, v);
            }
        }
    }
    __syncthreads();
    // L3: C3 = P0 @ plW0_top   |   L4: Hp = relu(Pr@ppW0 + b0p)
    f32x4 C3[2][2];
#pragma unroll
    for (int ii = 0; ii < 2; ++ii)
#pragma unroll
        for (int nt = 0; nt < 2; ++nt) C3[ii][nt] = (f32x4){0.f, 0.f, 0.f, 0.f};
    gemm2<4, 2>(g_Wf + OFF_PL0T, sP0F, mt0, lane, C3);
    {
        f32x4 aH[2][2];
#pragma unroll
        for (int ii = 0; ii < 2; ++ii)
#pragma unroll
            for (int nt = 0; nt < 2; ++nt) aH[ii][nt] = (f32x4){0.f, 0.f, 0.f, 0.f};
        gemm2<1, 2>(g_Wf + OFF_PP0, sPrF, mt0, lane, aH);
        EPI_RELU_STORE(aH, sBpp0, sHpF, 2);
    }
    __syncthreads();
    // L5: P1 = relu(Hp@ppW1 + b1p) -> reuse sH0F
    {
        f32x4 aP[2][2];
#pragma unroll
        for (int ii = 0; ii < 2; ++ii)
#pragma unroll
            for (int nt = 0; nt < 2; ++nt) aP[ii][nt] = (f32x4){0.f, 0.f, 0.f, 0.f};
        gemm2<4, 2>(g_Wf + OFF_PP1, sHpF, mt0, lane, aP);
        EPI_RELU_STORE(aP, sBpp1, sH0F, 2);
    }
    __syncthreads();
    // L6: C3 += P1 @ plW0_bot ; Hl = relu(C3 + b0l) -> reuse sH1F
    gemm2<4, 2>(g_Wf + OFF_PL0B, sH0F, mt0, lane, C3);
    EPI_RELU_STORE(C3, sBpl0, sH1F, 2);
    __syncthreads();
    // L7: out = relu(Hl@plW1 + b1l)
    {
        f32x4 aO[2][2];
#pragma unroll
        for (int ii = 0; ii < 2; ++ii)
#pragma unroll
            for (int nt = 0; nt < 2; ++nt) aO[ii][nt] = (f32x4){0.f, 0.f, 0.f, 0.f};
        gemm2<4, 2>(g_Wf + OFF_PL1, sH1F, mt0, lane, aO);
        int c = lane & 15, quad = lane >> 4;
        const size_t NA = (size_t)B_ * N_ * C_;   // 524288
#pragma unroll
        for (int ii = 0; ii < 2; ++ii) {
            int mt = mt0 + ii;
            f32x4 bb = *(const f32x4*)&sBpl1[mt * 16 + quad * 4];
#pragma unroll
            for (int nt = 0; nt < 2; ++nt) {
                f32x4 v;
#pragma unroll
                for (int r = 0; r < 4; ++r) { float x = aO[ii][nt][r] + bb[r]; v[r] = x > 0.f ? x : 0.f; }
                store_out4(out, NA + (prow0 + nt * 16 + c) * 128 + mt * 16 + quad * 4, v, isbf);
            }
        }
    }
}

extern "C" void kernel_launch(void* const* d_in, const int* in_sizes, int n_in,
                              void* d_out, int out_size, void* d_ws, size_t ws_size,
                              hipStream_t stream) {
    const void* atom  = d_in[0];
    const void* pairx = d_in[1];
    const void* aaW0 = d_in[2];  const void* aaB0 = d_in[3];
    const void* aaW1 = d_in[4];  const void* aaB1 = d_in[5];
    const void* paW0 = d_in[6];  const void* paB0 = d_in[7];
    const void* paW1 = d_in[8];  const void* paB1 = d_in[9];
    const void* alW0 = d_in[10]; const void* alB0 = d_in[11];
    const void* alW1 = d_in[12]; const void* alB1 = d_in[13];
    const void* apW0 = d_in[14]; const void* apB0 = d_in[15];
    const void* apW1 = d_in[16]; const void* apB1 = d_in[17];
    const void* ppW0 = d_in[18]; const void* ppB0 = d_in[19];
    const void* ppW1 = d_in[20]; const void* ppB1 = d_in[21];
    const void* plW0 = d_in[22]; const void* plB0 = d_in[23];
    const void* plW1 = d_in[24]; const void* plB1 = d_in[25];
    (void)d_ws; (void)ws_size; (void)in_sizes; (void)n_in; (void)out_size;

    detect_k<<<1, 64, 0, stream>>>(atom);
    prep_w<<<102, 256, 0, stream>>>(aaW0, aaW1, apW0, paW0, paW1, alW0, alW1,
                                    apW1, ppW0, ppW1, plW0, plW1);
    atom_pre<<<64, 256, 0, stream>>>(atom, aaB0, aaB1);
    p2a_sum<<<4096, 256, 0, stream>>>(pairx, paB0, paB1);
    atom_layer<<<128, 256, 0, stream>>>(alB0, alB1, d_out);
    pair_fused<<<8192, 256, 0, stream>>>(pairx, apB0, apB1, ppB0, ppB1,
                                         plB0, plB1, d_out);
}

// Round 5
// 325.593 us; speedup vs baseline: 9.4210x; 1.0688x over previous
//
#include <hip/hip_runtime.h>
#include <hip/hip_bf16.h>

typedef unsigned short u16;
typedef unsigned int u32;
typedef __attribute__((ext_vector_type(8))) __bf16 bf16x8;
typedef __attribute__((ext_vector_type(4))) float f32x4;

#define B_ 64
#define N_ 64
#define FA_ 75
#define FP_ 14
#define C_ 128

// ---- static device scratch (fully rewritten every call) ----
__device__ float g_A0[4096 * 128];   // a0 branch, fp32 [row][feat]
__device__ float g_A1[4096 * 128];   // p2a-summed branch, fp32
__device__ float g_TB[4096 * 256];   // [T | Bo] per atom row, fp32
__device__ u16   g_Wf[208896];       // all weights in A-fragment layout (bf16)
__device__ int   g_isbf;             // 1=bf16 inputs, 0=fp32 inputs

// frag-weight offsets (u16 elements); layout slot = ((mt*KS+ks)*64+lane)*8+j
#define OFF_AA0   0
#define OFF_AA1   12288
#define OFF_APT   28672
#define OFF_APB   40960
#define OFF_PA0   53248
#define OFF_PA1   57344
#define OFF_AL0   73728
#define OFF_AL1   106496
#define OFF_AP1   122880
#define OFF_PP0   139264
#define OFF_PP1   143360
#define OFF_PL0T  159744
#define OFF_PL0B  176128
#define OFF_PL1   192512

__device__ __forceinline__ float bf2f(u16 a) {
    union { u32 u; float f; } v; v.u = ((u32)a) << 16; return v.f;
}
__device__ __forceinline__ u16 f2bf(float f) {
    union { float f; u32 u; } v; v.f = f;
    u32 r = v.u + 0x7fffu + ((v.u >> 16) & 1u);   // RNE
    return (u16)(r >> 16);
}
#if __has_builtin(__builtin_amdgcn_cvt_pk_bf16_f32)
__device__ __forceinline__ u32 f2bf_pk(float a, float b) {
    auto r = __builtin_amdgcn_cvt_pk_bf16_f32(a, b);
    if constexpr (sizeof(r) == 4) {
        union { decltype(r) v; u32 u; } c; c.v = r; return c.u;
    } else {
        return (u32)f2bf(a) | ((u32)f2bf(b) << 16);
    }
}
#else
__device__ __forceinline__ u32 f2bf_pk(float a, float b) {
    return (u32)f2bf(a) | ((u32)f2bf(b) << 16);
}
#endif

__device__ __forceinline__ u16 ldw(const void* p, size_t i, bool isbf) {
    if (isbf) return ((const u16*)p)[i];
    return f2bf(((const float*)p)[i]);
}
__device__ __forceinline__ float ldf(const void* p, size_t i, bool isbf) {
    if (isbf) return bf2f(((const u16*)p)[i]);
    return ((const float*)p)[i];
}
__device__ __forceinline__ f32x4 ldf4(const void* p, int i, bool isbf) {
    f32x4 r;
    if (isbf) {
        const u16* q = (const u16*)p + i;
        r[0] = bf2f(q[0]); r[1] = bf2f(q[1]); r[2] = bf2f(q[2]); r[3] = bf2f(q[3]);
    } else {
        r = *(const f32x4*)((const float*)p + i);
    }
    return r;
}
// pack 8 row elements k0..k0+7 (zero-padded past kmax) into bf16x8 frag word
__device__ __forceinline__ uint4 pack8(const void* p, size_t base, int kmax, int k0, bool isbf) {
    uint4 u;
    if (isbf) {
        const u16* q = (const u16*)p + base;
        u16 h[8];
#pragma unroll
        for (int j = 0; j < 8; ++j) h[j] = (k0 + j < kmax) ? q[k0 + j] : (u16)0;
        u.x = (u32)h[0] | ((u32)h[1] << 16); u.y = (u32)h[2] | ((u32)h[3] << 16);
        u.z = (u32)h[4] | ((u32)h[5] << 16); u.w = (u32)h[6] | ((u32)h[7] << 16);
    } else {
        const float* q = (const float*)p + base;
        float f[8];
#pragma unroll
        for (int j = 0; j < 8; ++j) f[j] = (k0 + j < kmax) ? q[k0 + j] : 0.f;
        u.x = f2bf_pk(f[0], f[1]); u.y = f2bf_pk(f[2], f[3]);
        u.z = f2bf_pk(f[4], f[5]); u.w = f2bf_pk(f[6], f[7]);
    }
    return u;
}

// ---------------- dtype detect ----------------
__global__ void detect_k(const void* __restrict__ atom) {
    if (threadIdx.x == 0) {
        const u32* a = (const u32*)atom;
        int sane = 0;
        for (int w = 0; w < 64; ++w) {
            u32 ex = (a[w] >> 7) & 0xffu;
            sane += (ex >= 113u && ex <= 133u) ? 1 : 0;
        }
        g_isbf = (sane >= 32) ? 1 : 0;
    }
}

// ---------------- weight prep: global [K][128] -> A-frag layout ----------------
__global__ __launch_bounds__(256) void prep_w(
    const void* aaW0, const void* aaW1, const void* apW0,
    const void* paW0, const void* paW1, const void* alW0, const void* alW1,
    const void* apW1, const void* ppW0, const void* ppW1,
    const void* plW0, const void* plW1) {
    const void* srcs[14] = {aaW0, aaW1, apW0, apW0, paW0, paW1, alW0, alW1,
                            apW1, ppW0, ppW1, plW0, plW0, plW1};
    const int Ktab[14]  = {75, 128, 75, 75, 14, 128, 256, 128, 128, 14, 128, 128, 128, 128};
    const int KStab[14] = {3, 4, 3, 3, 1, 4, 8, 4, 4, 1, 4, 4, 4, 4};
    const int rofft[14] = {0, 0, 0, 75, 0, 0, 0, 0, 0, 0, 0, 0, 128, 0};
    const int baset[14] = {OFF_AA0, OFF_AA1, OFF_APT, OFF_APB, OFF_PA0, OFF_PA1,
                           OFF_AL0, OFF_AL1, OFF_AP1, OFF_PP0, OFF_PP1,
                           OFF_PL0T, OFF_PL0B, OFF_PL1};
    int gid = blockIdx.x * 256 + threadIdx.x;
    int j = 0, s = gid;
    while (j < 14 && s >= KStab[j] * 512) { s -= KStab[j] * 512; ++j; }
    if (j >= 14) return;
    const bool isbf = g_isbf != 0;
    int lane = s & 63, rest = s >> 6;
    int ks = rest % KStab[j], mt = rest / KStab[j];
    int m = mt * 16 + (lane & 15), q = lane >> 4;
    float f[8];
#pragma unroll
    for (int jj = 0; jj < 8; ++jj) {
        int k = ks * 32 + q * 8 + jj;
        f[jj] = (k < Ktab[j]) ? ldf(srcs[j], (size_t)(rofft[j] + k) * 128 + m, isbf) : 0.f;
    }
    uint4 u;
    u.x = f2bf_pk(f[0], f[1]); u.y = f2bf_pk(f[2], f[3]);
    u.z = f2bf_pk(f[4], f[5]); u.w = f2bf_pk(f[6], f[7]);
    *(uint4*)&g_Wf[(size_t)baset[j] + (size_t)s * 8] = u;
}

// ---------------- MFMA GEMM core ----------------
template<int KS, int NT>
__device__ __forceinline__ void gemm2(const u16* __restrict__ wf,
                                      const u16* __restrict__ bF,
                                      int mt0, int lane, f32x4 (&acc)[2][NT]) {
#pragma unroll
    for (int ks = 0; ks < KS; ++ks) {
        bf16x8 a0 = *(const bf16x8*)(wf + (((mt0    ) * KS + ks) * 64 + lane) * 8);
        bf16x8 a1 = *(const bf16x8*)(wf + (((mt0 + 1) * KS + ks) * 64 + lane) * 8);
#pragma unroll
        for (int nt = 0; nt < NT; ++nt) {
            bf16x8 b = *(const bf16x8*)(bF + ((nt * KS + ks) * 64 + lane) * 8);
            acc[0][nt] = __builtin_amdgcn_mfma_f32_16x16x32_bf16(a0, b, acc[0][nt], 0, 0, 0);
            acc[1][nt] = __builtin_amdgcn_mfma_f32_16x16x32_bf16(a1, b, acc[1][nt], 0, 0, 0);
        }
    }
}

// C-frag -> next-layer B-frag store (one uint2 per frag per lane)
__device__ __forceinline__ void frag_store(u16* dstF, int KSd, int nt, int mt, int lane, f32x4 v) {
    int c = lane & 15, quad = lane >> 4;
    int lp = c + 16 * ((2 * mt + (quad >> 1)) & 3);
    int ks = mt >> 1;
    uint2 u; u.x = f2bf_pk(v[0], v[1]); u.y = f2bf_pk(v[2], v[3]);
    *(uint2*)(dstF + (((nt * KSd + ks) * 64 + lp) * 8 + (quad & 1) * 4)) = u;
}

__device__ __forceinline__ void store_out4(void* outp, size_t elem, f32x4 v, bool isbf) {
    if (isbf) {
        uint2 u; u.x = f2bf_pk(v[0], v[1]); u.y = f2bf_pk(v[2], v[3]);
        *(uint2*)((u16*)outp + elem) = u;
    } else {
        *(f32x4*)((float*)outp + elem) = v;
    }
}

#define EPI_RELU_STORE(ACC, BB0, BB1, DST, NTN) do {                             \
    _Pragma("unroll") for (int ii = 0; ii < 2; ++ii) {                           \
        f32x4 bb_ = ii ? (BB1) : (BB0);                                          \
        _Pragma("unroll") for (int nt_ = 0; nt_ < NTN; ++nt_) {                  \
            f32x4 v_;                                                            \
            _Pragma("unroll") for (int r_ = 0; r_ < 4; ++r_) {                   \
                float x_ = ACC[ii][nt_][r_] + bb_[r_];                           \
                v_[r_] = x_ > 0.f ? x_ : 0.f;                                    \
            }                                                                    \
            frag_store(DST, 4, nt_, mt0 + ii, lane, v_);                         \
        }                                                                        \
    }                                                                            \
} while (0)

// ---------------- Kernel: atom branch pre-work ----------------
__global__ __launch_bounds__(256) void atom_pre(
    const void* __restrict__ atom,
    const void* __restrict__ aaB0, const void* __restrict__ aaB1) {
    __shared__ __align__(16) u16 sXF[4 * 3 * 64 * 8];   // 12KB
    __shared__ __align__(16) u16 sHF[4 * 4 * 64 * 8];   // 16KB
    const bool isbf = g_isbf != 0;
    const int t = threadIdx.x, lane = t & 63, w = t >> 6;
    const int quad = lane >> 4;
    const int b = blockIdx.x;
    for (int s = t; s < 4 * 3 * 64; s += 256) {
        int lane_s = s & 63, rest = s >> 6;
        int ks = rest % 3, nt = rest / 3;
        int n = nt * 16 + (lane_s & 15), q = lane_s >> 4;
        *(uint4*)&sXF[s * 8] = pack8(atom, (size_t)(b * 64 + n) * FA_, FA_, ks * 32 + q * 8, isbf);
    }
    __syncthreads();
    const int mt0 = 2 * w;
    {
        f32x4 bb0 = ldf4(aaB0, mt0 * 16 + quad * 4, isbf);
        f32x4 bb1 = ldf4(aaB0, (mt0 + 1) * 16 + quad * 4, isbf);
        f32x4 acc[2][4];
#pragma unroll
        for (int ii = 0; ii < 2; ++ii)
#pragma unroll
            for (int nt = 0; nt < 4; ++nt) acc[ii][nt] = (f32x4){0.f, 0.f, 0.f, 0.f};
        gemm2<3, 4>(g_Wf + OFF_AA0, sXF, mt0, lane, acc);
        EPI_RELU_STORE(acc, bb0, bb1, sHF, 4);
    }
    __syncthreads();
    {
        f32x4 bb0 = ldf4(aaB1, mt0 * 16 + quad * 4, isbf);
        f32x4 bb1 = ldf4(aaB1, (mt0 + 1) * 16 + quad * 4, isbf);
        f32x4 acc[2][4];
#pragma unroll
        for (int ii = 0; ii < 2; ++ii)
#pragma unroll
            for (int nt = 0; nt < 4; ++nt) acc[ii][nt] = (f32x4){0.f, 0.f, 0.f, 0.f};
        gemm2<4, 4>(g_Wf + OFF_AA1, sHF, mt0, lane, acc);
        int c = lane & 15;
#pragma unroll
        for (int ii = 0; ii < 2; ++ii) {
            int mt = mt0 + ii;
            f32x4 bb = ii ? bb1 : bb0;
#pragma unroll
            for (int nt = 0; nt < 4; ++nt) {
                f32x4 v;
#pragma unroll
                for (int r = 0; r < 4; ++r) { float x = acc[ii][nt][r] + bb[r]; v[r] = x > 0.f ? x : 0.f; }
                *(f32x4*)&g_A0[(size_t)(b * 64 + nt * 16 + c) * 128 + mt * 16 + quad * 4] = v;
            }
        }
    }
    {
        f32x4 accT[2][4], accB[2][4];
#pragma unroll
        for (int ii = 0; ii < 2; ++ii)
#pragma unroll
            for (int nt = 0; nt < 4; ++nt) { accT[ii][nt] = (f32x4){0.f,0.f,0.f,0.f}; accB[ii][nt] = (f32x4){0.f,0.f,0.f,0.f}; }
        gemm2<3, 4>(g_Wf + OFF_APT, sXF, mt0, lane, accT);
        gemm2<3, 4>(g_Wf + OFF_APB, sXF, mt0, lane, accB);
        int c = lane & 15;
#pragma unroll
        for (int ii = 0; ii < 2; ++ii) {
            int mt = mt0 + ii;
#pragma unroll
            for (int nt = 0; nt < 4; ++nt) {
                size_t row = (size_t)(b * 64 + nt * 16 + c);
                *(f32x4*)&g_TB[row * 256 + mt * 16 + quad * 4] = accT[ii][nt];
                *(f32x4*)&g_TB[row * 256 + 128 + mt * 16 + quad * 4] = accB[ii][nt];
            }
        }
    }
}

// ---------------- Kernel: PairToAtom (per (b,i); sum over 64 rows) ----------------
__global__ __launch_bounds__(256) void p2a_sum(
    const void* __restrict__ pairx,
    const void* __restrict__ paB0, const void* __restrict__ paB1) {
    __shared__ __align__(16) u16 sPF[4 * 1 * 64 * 8];   // 4KB
    __shared__ __align__(16) u16 sHF[4 * 4 * 64 * 8];   // 16KB
    const bool isbf = g_isbf != 0;
    const int t = threadIdx.x, lane = t & 63, w = t >> 6;
    const int quad = lane >> 4;
    const int bx = blockIdx.x;
    const size_t rbase = (size_t)bx * 64;
    {
        int lane_s = t & 63, nt = t >> 6;
        int n = nt * 16 + (lane_s & 15), q = lane_s >> 4;
        *(uint4*)&sPF[t * 8] = pack8(pairx, (rbase + n) * FP_, FP_, q * 8, isbf);
    }
    __syncthreads();
    const int mt0 = 2 * w;
    {
        f32x4 bb0 = ldf4(paB0, mt0 * 16 + quad * 4, isbf);
        f32x4 bb1 = ldf4(paB0, (mt0 + 1) * 16 + quad * 4, isbf);
        f32x4 acc[2][4];
#pragma unroll
        for (int ii = 0; ii < 2; ++ii)
#pragma unroll
            for (int nt = 0; nt < 4; ++nt) acc[ii][nt] = (f32x4){0.f, 0.f, 0.f, 0.f};
        gemm2<1, 4>(g_Wf + OFF_PA0, sPF, mt0, lane, acc);
        EPI_RELU_STORE(acc, bb0, bb1, sHF, 4);
    }
    __syncthreads();
    {
        f32x4 bb0 = ldf4(paB1, mt0 * 16 + quad * 4, isbf);
        f32x4 bb1 = ldf4(paB1, (mt0 + 1) * 16 + quad * 4, isbf);
        f32x4 acc[2][4];
#pragma unroll
        for (int ii = 0; ii < 2; ++ii)
#pragma unroll
            for (int nt = 0; nt < 4; ++nt) acc[ii][nt] = (f32x4){0.f, 0.f, 0.f, 0.f};
        gemm2<4, 4>(g_Wf + OFF_PA1, sHF, mt0, lane, acc);
#pragma unroll
        for (int ii = 0; ii < 2; ++ii) {
            int mt = mt0 + ii;
            f32x4 bb = ii ? bb1 : bb0;
            f32x4 ssum = (f32x4){0.f, 0.f, 0.f, 0.f};
#pragma unroll
            for (int nt = 0; nt < 4; ++nt)
#pragma unroll
                for (int r = 0; r < 4; ++r) {
                    float x = acc[ii][nt][r] + bb[r];
                    ssum[r] += (x > 0.f ? x : 0.f);
                }
#pragma unroll
            for (int m = 1; m < 16; m <<= 1)
#pragma unroll
                for (int r = 0; r < 4; ++r) ssum[r] += __shfl_xor(ssum[r], m, 64);
            if ((lane & 15) == 0)
                *(f32x4*)&g_A1[(size_t)bx * 128 + mt * 16 + quad * 4] = ssum;
        }
    }
}

// ---------------- Kernel: atom_layer (32 rows/block, K=256 then 128) --------------
__global__ __launch_bounds__(256) void atom_layer(
    const void* __restrict__ alB0, const void* __restrict__ alB1,
    void* __restrict__ out) {
    __shared__ __align__(16) u16 sXF[2 * 8 * 64 * 8];   // 16KB
    __shared__ __align__(16) u16 sHF[2 * 4 * 64 * 8];   // 8KB
    const bool isbf = g_isbf != 0;
    const int t = threadIdx.x, lane = t & 63, w = t >> 6;
    const int quad = lane >> 4;
    const int r0g = blockIdx.x * 32;
    for (int s = t; s < 2 * 8 * 64; s += 256) {
        int lane_s = s & 63, rest = s >> 6;
        int ks = rest & 7, nt = rest >> 3;
        int n = nt * 16 + (lane_s & 15), q = lane_s >> 4;
        int k0 = ks * 32 + q * 8;
        const float* src = (k0 < 128) ? &g_A0[(size_t)(r0g + n) * 128 + k0]
                                      : &g_A1[(size_t)(r0g + n) * 128 + (k0 - 128)];
        f32x4 f0 = *(const f32x4*)src, f1 = *(const f32x4*)(src + 4);
        uint4 u;
        u.x = f2bf_pk(f0[0], f0[1]); u.y = f2bf_pk(f0[2], f0[3]);
        u.z = f2bf_pk(f1[0], f1[1]); u.w = f2bf_pk(f1[2], f1[3]);
        *(uint4*)&sXF[s * 8] = u;
    }
    __syncthreads();
    const int mt0 = 2 * w;
    {
        f32x4 bb0 = ldf4(alB0, mt0 * 16 + quad * 4, isbf);
        f32x4 bb1 = ldf4(alB0, (mt0 + 1) * 16 + quad * 4, isbf);
        f32x4 acc[2][2];
#pragma unroll
        for (int ii = 0; ii < 2; ++ii)
#pragma unroll
            for (int nt = 0; nt < 2; ++nt) acc[ii][nt] = (f32x4){0.f, 0.f, 0.f, 0.f};
        gemm2<8, 2>(g_Wf + OFF_AL0, sXF, mt0, lane, acc);
        EPI_RELU_STORE(acc, bb0, bb1, sHF, 2);
    }
    __syncthreads();
    {
        f32x4 bb0 = ldf4(alB1, mt0 * 16 + quad * 4, isbf);
        f32x4 bb1 = ldf4(alB1, (mt0 + 1) * 16 + quad * 4, isbf);
        f32x4 acc[2][2];
#pragma unroll
        for (int ii = 0; ii < 2; ++ii)
#pragma unroll
            for (int nt = 0; nt < 2; ++nt) acc[ii][nt] = (f32x4){0.f, 0.f, 0.f, 0.f};
        gemm2<4, 2>(g_Wf + OFF_AL1, sHF, mt0, lane, acc);
        int c = lane & 15;
#pragma unroll
        for (int ii = 0; ii < 2; ++ii) {
            int mt = mt0 + ii;
            f32x4 bb = ii ? bb1 : bb0;
#pragma unroll
            for (int nt = 0; nt < 2; ++nt) {
                f32x4 v;
#pragma unroll
                for (int r = 0; r < 4; ++r) { float x = acc[ii][nt][r] + bb[r]; v[r] = x > 0.f ? x : 0.f; }
                store_out4(out, (size_t)(r0g + nt * 16 + c) * 128 + mt * 16 + quad * 4, v, isbf);
            }
        }
    }
}

// ---------------- Kernel: fused pair branch (32 rows/block, 24.6KB LDS) -----------
__global__ __launch_bounds__(256, 4) void pair_fused(
    const void* __restrict__ pairx,
    const void* __restrict__ apB0, const void* __restrict__ apB1,
    const void* __restrict__ ppB0, const void* __restrict__ ppB1,
    const void* __restrict__ plB0, const void* __restrict__ plB1,
    void* __restrict__ out) {
    // 3 rotating 8KB frag buffers; R doubles as {Pr frags + Tip/Bip} early, X3(P0) later.
    __shared__ __align__(16) u16 sPool[3 * 4096];
    u16* sX1 = sPool;              // H0 -> Hp -> Hl
    u16* sX2 = sPool + 4096;       // H1 -> P1
    u16* sR  = sPool + 8192;       // [Pr 1024u16 | Tip 128f | Bip 128f] -> X3 (P0)
    u16* sPrF = sR;
    float* sTip = (float*)(sR + 1024);
    float* sBip = sTip + 128;
    const bool isbf = g_isbf != 0;
    const int t = threadIdx.x, lane = t & 63, w = t >> 6;
    const int quad = lane >> 4, c = lane & 15;
    const int bx = blockIdx.x;
    const int b = bx >> 7, i = (bx >> 1) & 63, half = bx & 1;
    const int jbase = half * 32, trow = b * 64;
    const size_t prow0 = (size_t)b * 4096 + i * 64 + jbase;
    const int mt0 = 2 * w;

    // ---- phase A: Pr frags + bias-folded Ti'/Bo_i' ----
    if (t < 128) {
        float b0 = ldf(apB0, t, isbf);
        sTip[t] = g_TB[(size_t)(trow + i) * 256 + t] + b0;
        sBip[t] = g_TB[(size_t)(trow + i) * 256 + 128 + t] + b0;
    } else {
        int s = t - 128;
        int lane_s = s & 63, nt = s >> 6;
        int n = nt * 16 + (lane_s & 15), q = lane_s >> 4;
        *(uint4*)&sPrF[s * 8] = pack8(pairx, (prow0 + n) * FP_, FP_, q * 8, isbf);
    }
    __syncthreads();
    // ---- phase B: H0 -> X1, H1 -> X2 (elementwise) ; Hp-pre-bias gemm -> regs ----
    for (int sid = t; sid < 1024; sid += 256) {
        int buf = sid >> 9, s = sid & 511;
        int lane_s = s & 63, rest = s >> 6;
        int ks = rest & 3, nt = rest >> 2;
        int n = nt * 16 + (lane_s & 15), q = lane_s >> 4;
        int k0 = ks * 32 + q * 8;
        const float* Bj = &g_TB[(size_t)(trow + jbase + n) * 256];
        float v[8];
        if (buf == 0) {
#pragma unroll
            for (int j = 0; j < 8; ++j) { float x = sTip[k0 + j] + Bj[128 + k0 + j]; v[j] = x > 0.f ? x : 0.f; }
        } else {
#pragma unroll
            for (int j = 0; j < 8; ++j) { float x = Bj[k0 + j] + sBip[k0 + j]; v[j] = x > 0.f ? x : 0.f; }
        }
        uint4 u;
        u.x = f2bf_pk(v[0], v[1]); u.y = f2bf_pk(v[2], v[3]);
        u.z = f2bf_pk(v[4], v[5]); u.w = f2bf_pk(v[6], v[7]);
        *(uint4*)&(buf == 0 ? sX1 : sX2)[s * 8] = u;
    }
    f32x4 aH[2][2];          // Hp pre-bias, carried in regs across the barrier
#pragma unroll
    for (int ii = 0; ii < 2; ++ii)
#pragma unroll
        for (int nt = 0; nt < 2; ++nt) aH[ii][nt] = (f32x4){0.f, 0.f, 0.f, 0.f};
    gemm2<1, 2>(g_Wf + OFF_PP0, sPrF, mt0, lane, aH);
    __syncthreads();
    // ---- phase C: P0 = relu(H0@apW1+b1) + relu(H1@apW1+b1) -> X3 (=R) ----
    {
        f32x4 bb0 = ldf4(apB1, mt0 * 16 + quad * 4, isbf);
        f32x4 bb1 = ldf4(apB1, (mt0 + 1) * 16 + quad * 4, isbf);
        f32x4 aA[2][2], aB[2][2];
#pragma unroll
        for (int ii = 0; ii < 2; ++ii)
#pragma unroll
            for (int nt = 0; nt < 2; ++nt) { aA[ii][nt] = (f32x4){0.f,0.f,0.f,0.f}; aB[ii][nt] = (f32x4){0.f,0.f,0.f,0.f}; }
        gemm2<4, 2>(g_Wf + OFF_AP1, sX1, mt0, lane, aA);
        gemm2<4, 2>(g_Wf + OFF_AP1, sX2, mt0, lane, aB);
#pragma unroll
        for (int ii = 0; ii < 2; ++ii) {
            int mt = mt0 + ii;
            f32x4 bb = ii ? bb1 : bb0;
#pragma unroll
            for (int nt = 0; nt < 2; ++nt) {
                f32x4 v;
#pragma unroll
                for (int r = 0; r < 4; ++r) {
                    float x = aA[ii][nt][r] + bb[r];
                    float y = aB[ii][nt][r] + bb[r];
                    v[r] = (x > 0.f ? x : 0.f) + (y > 0.f ? y : 0.f);
                }
                frag_store(sR, 4, nt, mt, lane, v);
            }
        }
    }
    __syncthreads();
    // ---- phase D: C3 = P0@plW0_top ; Hp = relu(aH + b0p) -> X1 ----
    f32x4 C3[2][2];
#pragma unroll
    for (int ii = 0; ii < 2; ++ii)
#pragma unroll
        for (int nt = 0; nt < 2; ++nt) C3[ii][nt] = (f32x4){0.f, 0.f, 0.f, 0.f};
    gemm2<4, 2>(g_Wf + OFF_PL0T, sR, mt0, lane, C3);
    {
        f32x4 bb0 = ldf4(ppB0, mt0 * 16 + quad * 4, isbf);
        f32x4 bb1 = ldf4(ppB0, (mt0 + 1) * 16 + quad * 4, isbf);
        EPI_RELU_STORE(aH, bb0, bb1, sX1, 2);
    }
    __syncthreads();
    // ---- phase E: P1 = relu(Hp@ppW1 + b1p) -> X2 ----
    {
        f32x4 bb0 = ldf4(ppB1, mt0 * 16 + quad * 4, isbf);
        f32x4 bb1 = ldf4(ppB1, (mt0 + 1) * 16 + quad * 4, isbf);
        f32x4 aP[2][2];
#pragma unroll
        for (int ii = 0; ii < 2; ++ii)
#pragma unroll
            for (int nt = 0; nt < 2; ++nt) aP[ii][nt] = (f32x4){0.f, 0.f, 0.f, 0.f};
        gemm2<4, 2>(g_Wf + OFF_PP1, sX1, mt0, lane, aP);
        EPI_RELU_STORE(aP, bb0, bb1, sX2, 2);
    }
    __syncthreads();
    // ---- phase F: C3 += P1@plW0_bot ; Hl = relu(C3 + b0l) -> X1 ----
    gemm2<4, 2>(g_Wf + OFF_PL0B, sX2, mt0, lane, C3);
    {
        f32x4 bb0 = ldf4(plB0, mt0 * 16 + quad * 4, isbf);
        f32x4 bb1 = ldf4(plB0, (mt0 + 1) * 16 + quad * 4, isbf);
        EPI_RELU_STORE(C3, bb0, bb1, sX1, 2);
    }
    __syncthreads();
    // ---- phase G: out = relu(Hl@plW1 + b1l) ----
    {
        f32x4 bb0 = ldf4(plB1, mt0 * 16 + quad * 4, isbf);
        f32x4 bb1 = ldf4(plB1, (mt0 + 1) * 16 + quad * 4, isbf);
        f32x4 aO[2][2];
#pragma unroll
        for (int ii = 0; ii < 2; ++ii)
#pragma unroll
            for (int nt = 0; nt < 2; ++nt) aO[ii][nt] = (f32x4){0.f, 0.f, 0.f, 0.f};
        gemm2<4, 2>(g_Wf + OFF_PL1, sX1, mt0, lane, aO);
        const size_t NA = (size_t)B_ * N_ * C_;   // 524288
#pragma unroll
        for (int ii = 0; ii < 2; ++ii) {
            int mt = mt0 + ii;
            f32x4 bb = ii ? bb1 : bb0;
#pragma unroll
            for (int nt = 0; nt < 2; ++nt) {
                f32x4 v;
#pragma unroll
                for (int r = 0; r < 4; ++r) { float x = aO[ii][nt][r] + bb[r]; v[r] = x > 0.f ? x : 0.f; }
                store_out4(out, NA + (prow0 + nt * 16 + c) * 128 + mt * 16 + quad * 4, v, isbf);
            }
        }
    }
}

extern "C" void kernel_launch(void* const* d_in, const int* in_sizes, int n_in,
                              void* d_out, int out_size, void* d_ws, size_t ws_size,
                              hipStream_t stream) {
    const void* atom  = d_in[0];
    const void* pairx = d_in[1];
    const void* aaW0 = d_in[2];  const void* aaB0 = d_in[3];
    const void* aaW1 = d_in[4];  const void* aaB1 = d_in[5];
    const void* paW0 = d_in[6];  const void* paB0 = d_in[7];
    const void* paW1 = d_in[8];  const void* paB1 = d_in[9];
    const void* alW0 = d_in[10]; const void* alB0 = d_in[11];
    const void* alW1 = d_in[12]; const void* alB1 = d_in[13];
    const void* apW0 = d_in[14]; const void* apB0 = d_in[15];
    const void* apW1 = d_in[16]; const void* apB1 = d_in[17];
    const void* ppW0 = d_in[18]; const void* ppB0 = d_in[19];
    const void* ppW1 = d_in[20]; const void* ppB1 = d_in[21];
    const void* plW0 = d_in[22]; const void* plB0 = d_in[23];
    const void* plW1 = d_in[24]; const void* plB1 = d_in[25];
    (void)d_ws; (void)ws_size; (void)in_sizes; (void)n_in; (void)out_size;

    detect_k<<<1, 64, 0, stream>>>(atom);
    prep_w<<<102, 256, 0, stream>>>(aaW0, aaW1, apW0, paW0, paW1, alW0, alW1,
                                    apW1, ppW0, ppW1, plW0, plW1);
    atom_pre<<<64, 256, 0, stream>>>(atom, aaB0, aaB1);
    p2a_sum<<<4096, 256, 0, stream>>>(pairx, paB0, paB1);
    atom_layer<<<128, 256, 0, stream>>>(alB0, alB1, d_out);
    pair_fused<<<8192, 256, 0, stream>>>(pairx, apB0, apB1, ppB0, ppB1,
                                         plB0, plB1, d_out);
}

// Round 6
// 307.990 us; speedup vs baseline: 9.9594x; 1.0572x over previous
//
#include <hip/hip_runtime.h>
#include <hip/hip_bf16.h>

typedef unsigned short u16;
typedef unsigned int u32;
typedef __attribute__((ext_vector_type(8))) __bf16 bf16x8;
typedef __attribute__((ext_vector_type(4))) float f32x4;

#define B_ 64
#define N_ 64
#define FA_ 75
#define FP_ 14
#define C_ 128

// ---- static device scratch (fully rewritten every call) ----
__device__ float g_A0[4096 * 128];   // a0 branch, fp32 [row][feat]
__device__ float g_A1[4096 * 128];   // p2a-summed branch, fp32
__device__ float g_TB[4096 * 256];   // [T | Bo] per atom row, fp32
__device__ u16   g_Wf[208896];       // all weights in A-fragment layout (bf16)
__device__ int   g_isbf;             // 1=bf16 inputs, 0=fp32 inputs

// frag-weight offsets (u16 elements); layout slot = ((mt*KS+ks)*64+lane)*8+j
#define OFF_AA0   0
#define OFF_AA1   12288
#define OFF_APT   28672
#define OFF_APB   40960
#define OFF_PA0   53248
#define OFF_PA1   57344
#define OFF_AL0   73728
#define OFF_AL1   106496
#define OFF_AP1   122880
#define OFF_PP0   139264
#define OFF_PP1   143360
#define OFF_PL0T  159744
#define OFF_PL0B  176128
#define OFF_PL1   192512

__device__ __forceinline__ float bf2f(u16 a) {
    union { u32 u; float f; } v; v.u = ((u32)a) << 16; return v.f;
}
__device__ __forceinline__ u16 f2bf(float f) {
    union { float f; u32 u; } v; v.f = f;
    u32 r = v.u + 0x7fffu + ((v.u >> 16) & 1u);   // RNE
    return (u16)(r >> 16);
}
#if __has_builtin(__builtin_amdgcn_cvt_pk_bf16_f32)
__device__ __forceinline__ u32 f2bf_pk(float a, float b) {
    auto r = __builtin_amdgcn_cvt_pk_bf16_f32(a, b);
    if constexpr (sizeof(r) == 4) {
        union { decltype(r) v; u32 u; } c; c.v = r; return c.u;
    } else {
        return (u32)f2bf(a) | ((u32)f2bf(b) << 16);
    }
}
#else
__device__ __forceinline__ u32 f2bf_pk(float a, float b) {
    return (u32)f2bf(a) | ((u32)f2bf(b) << 16);
}
#endif

__device__ __forceinline__ u16 ldw(const void* p, size_t i, bool isbf) {
    if (isbf) return ((const u16*)p)[i];
    return f2bf(((const float*)p)[i]);
}
__device__ __forceinline__ float ldf(const void* p, size_t i, bool isbf) {
    if (isbf) return bf2f(((const u16*)p)[i]);
    return ((const float*)p)[i];
}
__device__ __forceinline__ f32x4 ldf4(const void* p, int i, bool isbf) {
    f32x4 r;
    if (isbf) {
        const u16* q = (const u16*)p + i;
        r[0] = bf2f(q[0]); r[1] = bf2f(q[1]); r[2] = bf2f(q[2]); r[3] = bf2f(q[3]);
    } else {
        r = *(const f32x4*)((const float*)p + i);
    }
    return r;
}
// pack 8 row elements k0..k0+7 (zero-padded past kmax) into bf16x8 frag word
__device__ __forceinline__ uint4 pack8(const void* p, size_t base, int kmax, int k0, bool isbf) {
    uint4 u;
    if (isbf) {
        const u16* q = (const u16*)p + base;
        u16 h[8];
#pragma unroll
        for (int j = 0; j < 8; ++j) h[j] = (k0 + j < kmax) ? q[k0 + j] : (u16)0;
        u.x = (u32)h[0] | ((u32)h[1] << 16); u.y = (u32)h[2] | ((u32)h[3] << 16);
        u.z = (u32)h[4] | ((u32)h[5] << 16); u.w = (u32)h[6] | ((u32)h[7] << 16);
    } else {
        const float* q = (const float*)p + base;
        float f[8];
#pragma unroll
        for (int j = 0; j < 8; ++j) f[j] = (k0 + j < kmax) ? q[k0 + j] : 0.f;
        u.x = f2bf_pk(f[0], f[1]); u.y = f2bf_pk(f[2], f[3]);
        u.z = f2bf_pk(f[4], f[5]); u.w = f2bf_pk(f[6], f[7]);
    }
    return u;
}

// ---------------- dtype detect ----------------
__global__ void detect_k(const void* __restrict__ atom) {
    if (threadIdx.x == 0) {
        const u32* a = (const u32*)atom;
        int sane = 0;
        for (int w = 0; w < 64; ++w) {
            u32 ex = (a[w] >> 7) & 0xffu;
            sane += (ex >= 113u && ex <= 133u) ? 1 : 0;
        }
        g_isbf = (sane >= 32) ? 1 : 0;
    }
}

// ---------------- weight prep: global [K][128] -> A-frag layout ----------------
__global__ __launch_bounds__(256) void prep_w(
    const void* aaW0, const void* aaW1, const void* apW0,
    const void* paW0, const void* paW1, const void* alW0, const void* alW1,
    const void* apW1, const void* ppW0, const void* ppW1,
    const void* plW0, const void* plW1) {
    const void* srcs[14] = {aaW0, aaW1, apW0, apW0, paW0, paW1, alW0, alW1,
                            apW1, ppW0, ppW1, plW0, plW0, plW1};
    const int Ktab[14]  = {75, 128, 75, 75, 14, 128, 256, 128, 128, 14, 128, 128, 128, 128};
    const int KStab[14] = {3, 4, 3, 3, 1, 4, 8, 4, 4, 1, 4, 4, 4, 4};
    const int rofft[14] = {0, 0, 0, 75, 0, 0, 0, 0, 0, 0, 0, 0, 128, 0};
    const int baset[14] = {OFF_AA0, OFF_AA1, OFF_APT, OFF_APB, OFF_PA0, OFF_PA1,
                           OFF_AL0, OFF_AL1, OFF_AP1, OFF_PP0, OFF_PP1,
                           OFF_PL0T, OFF_PL0B, OFF_PL1};
    int gid = blockIdx.x * 256 + threadIdx.x;
    int j = 0, s = gid;
    while (j < 14 && s >= KStab[j] * 512) { s -= KStab[j] * 512; ++j; }
    if (j >= 14) return;
    const bool isbf = g_isbf != 0;
    int lane = s & 63, rest = s >> 6;
    int ks = rest % KStab[j], mt = rest / KStab[j];
    int m = mt * 16 + (lane & 15), q = lane >> 4;
    float f[8];
#pragma unroll
    for (int jj = 0; jj < 8; ++jj) {
        int k = ks * 32 + q * 8 + jj;
        f[jj] = (k < Ktab[j]) ? ldf(srcs[j], (size_t)(rofft[j] + k) * 128 + m, isbf) : 0.f;
    }
    uint4 u;
    u.x = f2bf_pk(f[0], f[1]); u.y = f2bf_pk(f[2], f[3]);
    u.z = f2bf_pk(f[4], f[5]); u.w = f2bf_pk(f[6], f[7]);
    *(uint4*)&g_Wf[(size_t)baset[j] + (size_t)s * 8] = u;
}

// ---------------- MFMA GEMM core ----------------
template<int KS, int NT>
__device__ __forceinline__ void gemm2(const u16* __restrict__ wf,
                                      const u16* __restrict__ bF,
                                      int mt0, int lane, f32x4 (&acc)[2][NT]) {
#pragma unroll
    for (int ks = 0; ks < KS; ++ks) {
        bf16x8 a0 = *(const bf16x8*)(wf + (((mt0    ) * KS + ks) * 64 + lane) * 8);
        bf16x8 a1 = *(const bf16x8*)(wf + (((mt0 + 1) * KS + ks) * 64 + lane) * 8);
#pragma unroll
        for (int nt = 0; nt < NT; ++nt) {
            bf16x8 b = *(const bf16x8*)(bF + ((nt * KS + ks) * 64 + lane) * 8);
            acc[0][nt] = __builtin_amdgcn_mfma_f32_16x16x32_bf16(a0, b, acc[0][nt], 0, 0, 0);
            acc[1][nt] = __builtin_amdgcn_mfma_f32_16x16x32_bf16(a1, b, acc[1][nt], 0, 0, 0);
        }
    }
}

// C-frag -> next-layer B-frag store (one uint2 per frag per lane)
__device__ __forceinline__ void frag_store(u16* dstF, int KSd, int nt, int mt, int lane, f32x4 v) {
    int c = lane & 15, quad = lane >> 4;
    int lp = c + 16 * ((2 * mt + (quad >> 1)) & 3);
    int ks = mt >> 1;
    uint2 u; u.x = f2bf_pk(v[0], v[1]); u.y = f2bf_pk(v[2], v[3]);
    *(uint2*)(dstF + (((nt * KSd + ks) * 64 + lp) * 8 + (quad & 1) * 4)) = u;
}

__device__ __forceinline__ void store_out4(void* outp, size_t elem, f32x4 v, bool isbf) {
    if (isbf) {
        uint2 u; u.x = f2bf_pk(v[0], v[1]); u.y = f2bf_pk(v[2], v[3]);
        *(uint2*)((u16*)outp + elem) = u;
    } else {
        *(f32x4*)((float*)outp + elem) = v;
    }
}

#define EPI_RELU_STORE(ACC, BB0, BB1, DST, NTN) do {                             \
    _Pragma("unroll") for (int ii = 0; ii < 2; ++ii) {                           \
        f32x4 bb_ = ii ? (BB1) : (BB0);                                          \
        _Pragma("unroll") for (int nt_ = 0; nt_ < NTN; ++nt_) {                  \
            f32x4 v_;                                                            \
            _Pragma("unroll") for (int r_ = 0; r_ < 4; ++r_) {                   \
                float x_ = ACC[ii][nt_][r_] + bb_[r_];                           \
                v_[r_] = x_ > 0.f ? x_ : 0.f;                                    \
            }                                                                    \
            frag_store(DST, 4, nt_, mt0 + ii, lane, v_);                         \
        }                                                                        \
    }                                                                            \
} while (0)

// ---------------- Kernel: atom branch pre-work (128 blocks, 32 rows each) ---------
__global__ __launch_bounds__(256) void atom_pre(
    const void* __restrict__ atom,
    const void* __restrict__ aaB0, const void* __restrict__ aaB1) {
    __shared__ __align__(16) u16 sXF[2 * 3 * 64 * 8];   // 6KB
    __shared__ __align__(16) u16 sHF[2 * 4 * 64 * 8];   // 8KB
    const bool isbf = g_isbf != 0;
    const int t = threadIdx.x, lane = t & 63, w = t >> 6;
    const int quad = lane >> 4;
    const int r0g = blockIdx.x * 32;     // global row base (b*64 + half*32)
    for (int s = t; s < 2 * 3 * 64; s += 256) {
        int lane_s = s & 63, rest = s >> 6;
        int ks = rest % 3, nt = rest / 3;
        int n = nt * 16 + (lane_s & 15), q = lane_s >> 4;
        *(uint4*)&sXF[s * 8] = pack8(atom, (size_t)(r0g + n) * FA_, FA_, ks * 32 + q * 8, isbf);
    }
    __syncthreads();
    const int mt0 = 2 * w;
    {
        f32x4 bb0 = ldf4(aaB0, mt0 * 16 + quad * 4, isbf);
        f32x4 bb1 = ldf4(aaB0, (mt0 + 1) * 16 + quad * 4, isbf);
        f32x4 acc[2][2];
#pragma unroll
        for (int ii = 0; ii < 2; ++ii)
#pragma unroll
            for (int nt = 0; nt < 2; ++nt) acc[ii][nt] = (f32x4){0.f, 0.f, 0.f, 0.f};
        gemm2<3, 2>(g_Wf + OFF_AA0, sXF, mt0, lane, acc);
        EPI_RELU_STORE(acc, bb0, bb1, sHF, 2);
    }
    __syncthreads();
    {
        f32x4 bb0 = ldf4(aaB1, mt0 * 16 + quad * 4, isbf);
        f32x4 bb1 = ldf4(aaB1, (mt0 + 1) * 16 + quad * 4, isbf);
        f32x4 acc[2][2];
#pragma unroll
        for (int ii = 0; ii < 2; ++ii)
#pragma unroll
            for (int nt = 0; nt < 2; ++nt) acc[ii][nt] = (f32x4){0.f, 0.f, 0.f, 0.f};
        gemm2<4, 2>(g_Wf + OFF_AA1, sHF, mt0, lane, acc);
        int c = lane & 15;
#pragma unroll
        for (int ii = 0; ii < 2; ++ii) {
            int mt = mt0 + ii;
            f32x4 bb = ii ? bb1 : bb0;
#pragma unroll
            for (int nt = 0; nt < 2; ++nt) {
                f32x4 v;
#pragma unroll
                for (int r = 0; r < 4; ++r) { float x = acc[ii][nt][r] + bb[r]; v[r] = x > 0.f ? x : 0.f; }
                *(f32x4*)&g_A0[(size_t)(r0g + nt * 16 + c) * 128 + mt * 16 + quad * 4] = v;
            }
        }
    }
    {
        f32x4 accT[2][2], accB[2][2];
#pragma unroll
        for (int ii = 0; ii < 2; ++ii)
#pragma unroll
            for (int nt = 0; nt < 2; ++nt) { accT[ii][nt] = (f32x4){0.f,0.f,0.f,0.f}; accB[ii][nt] = (f32x4){0.f,0.f,0.f,0.f}; }
        gemm2<3, 2>(g_Wf + OFF_APT, sXF, mt0, lane, accT);
        gemm2<3, 2>(g_Wf + OFF_APB, sXF, mt0, lane, accB);
        int c = lane & 15;
#pragma unroll
        for (int ii = 0; ii < 2; ++ii) {
            int mt = mt0 + ii;
#pragma unroll
            for (int nt = 0; nt < 2; ++nt) {
                size_t row = (size_t)(r0g + nt * 16 + c);
                *(f32x4*)&g_TB[row * 256 + mt * 16 + quad * 4] = accT[ii][nt];
                *(f32x4*)&g_TB[row * 256 + 128 + mt * 16 + quad * 4] = accB[ii][nt];
            }
        }
    }
}

// ---------------- Kernel: PairToAtom (per (b,i); sum over 64 rows) ----------------
__global__ __launch_bounds__(256) void p2a_sum(
    const void* __restrict__ pairx,
    const void* __restrict__ paB0, const void* __restrict__ paB1) {
    __shared__ __align__(16) u16 sPF[4 * 1 * 64 * 8];   // 4KB
    __shared__ __align__(16) u16 sHF[4 * 4 * 64 * 8];   // 16KB
    const bool isbf = g_isbf != 0;
    const int t = threadIdx.x, lane = t & 63, w = t >> 6;
    const int quad = lane >> 4;
    const int bx = blockIdx.x;
    const size_t rbase = (size_t)bx * 64;
    {
        int lane_s = t & 63, nt = t >> 6;
        int n = nt * 16 + (lane_s & 15), q = lane_s >> 4;
        *(uint4*)&sPF[t * 8] = pack8(pairx, (rbase + n) * FP_, FP_, q * 8, isbf);
    }
    __syncthreads();
    const int mt0 = 2 * w;
    {
        f32x4 bb0 = ldf4(paB0, mt0 * 16 + quad * 4, isbf);
        f32x4 bb1 = ldf4(paB0, (mt0 + 1) * 16 + quad * 4, isbf);
        f32x4 acc[2][4];
#pragma unroll
        for (int ii = 0; ii < 2; ++ii)
#pragma unroll
            for (int nt = 0; nt < 4; ++nt) acc[ii][nt] = (f32x4){0.f, 0.f, 0.f, 0.f};
        gemm2<1, 4>(g_Wf + OFF_PA0, sPF, mt0, lane, acc);
        EPI_RELU_STORE(acc, bb0, bb1, sHF, 4);
    }
    __syncthreads();
    {
        f32x4 bb0 = ldf4(paB1, mt0 * 16 + quad * 4, isbf);
        f32x4 bb1 = ldf4(paB1, (mt0 + 1) * 16 + quad * 4, isbf);
        f32x4 acc[2][4];
#pragma unroll
        for (int ii = 0; ii < 2; ++ii)
#pragma unroll
            for (int nt = 0; nt < 4; ++nt) acc[ii][nt] = (f32x4){0.f, 0.f, 0.f, 0.f};
        gemm2<4, 4>(g_Wf + OFF_PA1, sHF, mt0, lane, acc);
#pragma unroll
        for (int ii = 0; ii < 2; ++ii) {
            int mt = mt0 + ii;
            f32x4 bb = ii ? bb1 : bb0;
            f32x4 ssum = (f32x4){0.f, 0.f, 0.f, 0.f};
#pragma unroll
            for (int nt = 0; nt < 4; ++nt)
#pragma unroll
                for (int r = 0; r < 4; ++r) {
                    float x = acc[ii][nt][r] + bb[r];
                    ssum[r] += (x > 0.f ? x : 0.f);
                }
#pragma unroll
            for (int m = 1; m < 16; m <<= 1)
#pragma unroll
                for (int r = 0; r < 4; ++r) ssum[r] += __shfl_xor(ssum[r], m, 64);
            if ((lane & 15) == 0)
                *(f32x4*)&g_A1[(size_t)bx * 128 + mt * 16 + quad * 4] = ssum;
        }
    }
}

// ---------------- Kernel: atom_layer (256 blocks, 16 rows each) -------------------
__global__ __launch_bounds__(256) void atom_layer(
    const void* __restrict__ alB0, const void* __restrict__ alB1,
    void* __restrict__ out) {
    __shared__ __align__(16) u16 sXF[1 * 8 * 64 * 8];   // 8KB
    __shared__ __align__(16) u16 sHF[1 * 4 * 64 * 8];   // 4KB
    const bool isbf = g_isbf != 0;
    const int t = threadIdx.x, lane = t & 63, w = t >> 6;
    const int quad = lane >> 4;
    const int r0g = blockIdx.x * 16;
    for (int s = t; s < 8 * 64; s += 256) {
        int lane_s = s & 63, ks = s >> 6;
        int n = lane_s & 15, q = lane_s >> 4;
        int k0 = ks * 32 + q * 8;
        const float* src = (k0 < 128) ? &g_A0[(size_t)(r0g + n) * 128 + k0]
                                      : &g_A1[(size_t)(r0g + n) * 128 + (k0 - 128)];
        f32x4 f0 = *(const f32x4*)src, f1 = *(const f32x4*)(src + 4);
        uint4 u;
        u.x = f2bf_pk(f0[0], f0[1]); u.y = f2bf_pk(f0[2], f0[3]);
        u.z = f2bf_pk(f1[0], f1[1]); u.w = f2bf_pk(f1[2], f1[3]);
        *(uint4*)&sXF[s * 8] = u;
    }
    __syncthreads();
    const int mt0 = 2 * w;
    {
        f32x4 bb0 = ldf4(alB0, mt0 * 16 + quad * 4, isbf);
        f32x4 bb1 = ldf4(alB0, (mt0 + 1) * 16 + quad * 4, isbf);
        f32x4 acc[2][1];
#pragma unroll
        for (int ii = 0; ii < 2; ++ii) acc[ii][0] = (f32x4){0.f, 0.f, 0.f, 0.f};
        gemm2<8, 1>(g_Wf + OFF_AL0, sXF, mt0, lane, acc);
        EPI_RELU_STORE(acc, bb0, bb1, sHF, 1);
    }
    __syncthreads();
    {
        f32x4 bb0 = ldf4(alB1, mt0 * 16 + quad * 4, isbf);
        f32x4 bb1 = ldf4(alB1, (mt0 + 1) * 16 + quad * 4, isbf);
        f32x4 acc[2][1];
#pragma unroll
        for (int ii = 0; ii < 2; ++ii) acc[ii][0] = (f32x4){0.f, 0.f, 0.f, 0.f};
        gemm2<4, 1>(g_Wf + OFF_AL1, sHF, mt0, lane, acc);
        int c = lane & 15;
#pragma unroll
        for (int ii = 0; ii < 2; ++ii) {
            int mt = mt0 + ii;
            f32x4 bb = ii ? bb1 : bb0;
            f32x4 v;
#pragma unroll
            for (int r = 0; r < 4; ++r) { float x = acc[ii][0][r] + bb[r]; v[r] = x > 0.f ? x : 0.f; }
            store_out4(out, (size_t)(r0g + c) * 128 + mt * 16 + quad * 4, v, isbf);
        }
    }
}

// ---------------- Kernel: fused pair branch (4096 blocks, 64 rows each) -----------
__global__ __launch_bounds__(256, 3) void pair_fused(
    const void* __restrict__ pairx,
    const void* __restrict__ apB0, const void* __restrict__ apB1,
    const void* __restrict__ ppB0, const void* __restrict__ ppB1,
    const void* __restrict__ plB0, const void* __restrict__ plB1,
    void* __restrict__ out) {
    __shared__ __align__(16) u16 sX1[4 * 4 * 64 * 8];   // 16KB  H0 -> Hp -> Hl
    __shared__ __align__(16) u16 sX2[4 * 4 * 64 * 8];   // 16KB  H1 -> P1
    __shared__ __align__(16) u16 sR [4 * 4 * 64 * 8];   // 16KB  P0
    __shared__ __align__(16) u16 sPr[4 * 1 * 64 * 8];   // 4KB   pair_x frags
    const bool isbf = g_isbf != 0;
    const int t = threadIdx.x, lane = t & 63, w = t >> 6;
    const int quad = lane >> 4, c = lane & 15;
    const int bx = blockIdx.x;
    const int b = bx >> 6, i = bx & 63;
    const int trow = b * 64;
    const size_t prow0 = (size_t)b * 4096 + (size_t)i * 64;
    const int mt0 = 2 * w;

    // ---- stage (no barriers yet): Pr frags + H0/H1 built from registers ----
    {
        int lane_s = t & 63, nt = t >> 6;
        int n = nt * 16 + (lane_s & 15), q = lane_s >> 4;
        *(uint4*)&sPr[t * 8] = pack8(pairx, (prow0 + n) * FP_, FP_, q * 8, isbf);
    }
    {
        const int ksg = t >> 6;               // this thread's ks segment
        const int k0 = ksg * 32 + quad * 8;   // fixed 8-wide k window
        const int rc = c;                     // row-class within each 16-row group
        // bias-folded Ti' / Bo_i' segments (wave-broadcast loads)
        const float* TBi = &g_TB[(size_t)(trow + i) * 256 + k0];
        f32x4 t0 = *(const f32x4*)TBi,        t1 = *(const f32x4*)(TBi + 4);
        f32x4 o0 = *(const f32x4*)(TBi + 128), o1 = *(const f32x4*)(TBi + 132);
        f32x4 b0a = ldf4(apB0, k0, isbf), b0b = ldf4(apB0, k0 + 4, isbf);
        float Tip[8], Bip[8];
#pragma unroll
        for (int r = 0; r < 4; ++r) {
            Tip[r] = t0[r] + b0a[r]; Tip[4 + r] = t1[r] + b0b[r];
            Bip[r] = o0[r] + b0a[r]; Bip[4 + r] = o1[r] + b0b[r];
        }
#pragma unroll
        for (int nt = 0; nt < 4; ++nt) {
            int n = nt * 16 + rc;
            const float* Bj = &g_TB[(size_t)(trow + n) * 256 + k0];
            f32x4 j0 = *(const f32x4*)Bj,        j1 = *(const f32x4*)(Bj + 4);
            f32x4 j2 = *(const f32x4*)(Bj + 128), j3 = *(const f32x4*)(Bj + 132);
            float v0[8], v1[8];
#pragma unroll
            for (int r = 0; r < 4; ++r) {
                float x0 = Tip[r] + j2[r];      v0[r]     = x0 > 0.f ? x0 : 0.f;  // H0
                float x1 = Tip[4 + r] + j3[r];  v0[4 + r] = x1 > 0.f ? x1 : 0.f;
                float y0 = j0[r] + Bip[r];      v1[r]     = y0 > 0.f ? y0 : 0.f;  // H1
                float y1 = j1[r] + Bip[4 + r];  v1[4 + r] = y1 > 0.f ? y1 : 0.f;
            }
            uint4 u0, u1;
            u0.x = f2bf_pk(v0[0], v0[1]); u0.y = f2bf_pk(v0[2], v0[3]);
            u0.z = f2bf_pk(v0[4], v0[5]); u0.w = f2bf_pk(v0[6], v0[7]);
            u1.x = f2bf_pk(v1[0], v1[1]); u1.y = f2bf_pk(v1[2], v1[3]);
            u1.z = f2bf_pk(v1[4], v1[5]); u1.w = f2bf_pk(v1[6], v1[7]);
            int slot = ((nt * 4 + ksg) * 64 + lane) * 8;
            *(uint4*)&sX1[slot] = u0;
            *(uint4*)&sX2[slot] = u1;
        }
    }
    __syncthreads();
    // ---- phase C: aH = Pr@ppW0 (regs) ; P0 = relu(H0@apW1+b1)+relu(H1@apW1+b1) -> sR
    f32x4 aH[2][4];
#pragma unroll
    for (int ii = 0; ii < 2; ++ii)
#pragma unroll
        for (int nt = 0; nt < 4; ++nt) aH[ii][nt] = (f32x4){0.f, 0.f, 0.f, 0.f};
    gemm2<1, 4>(g_Wf + OFF_PP0, sPr, mt0, lane, aH);
    {
        f32x4 bb0 = ldf4(apB1, mt0 * 16 + quad * 4, isbf);
        f32x4 bb1 = ldf4(apB1, (mt0 + 1) * 16 + quad * 4, isbf);
        f32x4 aA[2][4], aB[2][4];
#pragma unroll
        for (int ii = 0; ii < 2; ++ii)
#pragma unroll
            for (int nt = 0; nt < 4; ++nt) { aA[ii][nt] = (f32x4){0.f,0.f,0.f,0.f}; aB[ii][nt] = (f32x4){0.f,0.f,0.f,0.f}; }
        gemm2<4, 4>(g_Wf + OFF_AP1, sX1, mt0, lane, aA);
        gemm2<4, 4>(g_Wf + OFF_AP1, sX2, mt0, lane, aB);
#pragma unroll
        for (int ii = 0; ii < 2; ++ii) {
            int mt = mt0 + ii;
            f32x4 bb = ii ? bb1 : bb0;
#pragma unroll
            for (int nt = 0; nt < 4; ++nt) {
                f32x4 v;
#pragma unroll
                for (int r = 0; r < 4; ++r) {
                    float x = aA[ii][nt][r] + bb[r];
                    float y = aB[ii][nt][r] + bb[r];
                    v[r] = (x > 0.f ? x : 0.f) + (y > 0.f ? y : 0.f);
                }
                frag_store(sR, 4, nt, mt, lane, v);
            }
        }
    }
    __syncthreads();
    // ---- phase D: C3 = P0@plW0_top ; Hp = relu(aH + b0p) -> sX1 ----
    f32x4 C3[2][4];
#pragma unroll
    for (int ii = 0; ii < 2; ++ii)
#pragma unroll
        for (int nt = 0; nt < 4; ++nt) C3[ii][nt] = (f32x4){0.f, 0.f, 0.f, 0.f};
    gemm2<4, 4>(g_Wf + OFF_PL0T, sR, mt0, lane, C3);
    {
        f32x4 bb0 = ldf4(ppB0, mt0 * 16 + quad * 4, isbf);
        f32x4 bb1 = ldf4(ppB0, (mt0 + 1) * 16 + quad * 4, isbf);
        EPI_RELU_STORE(aH, bb0, bb1, sX1, 4);
    }
    __syncthreads();
    // ---- phase E: P1 = relu(Hp@ppW1 + b1p) -> sX2 ----
    {
        f32x4 bb0 = ldf4(ppB1, mt0 * 16 + quad * 4, isbf);
        f32x4 bb1 = ldf4(ppB1, (mt0 + 1) * 16 + quad * 4, isbf);
        f32x4 aP[2][4];
#pragma unroll
        for (int ii = 0; ii < 2; ++ii)
#pragma unroll
            for (int nt = 0; nt < 4; ++nt) aP[ii][nt] = (f32x4){0.f, 0.f, 0.f, 0.f};
        gemm2<4, 4>(g_Wf + OFF_PP1, sX1, mt0, lane, aP);
        EPI_RELU_STORE(aP, bb0, bb1, sX2, 4);
    }
    __syncthreads();
    // ---- phase F: C3 += P1@plW0_bot ; Hl = relu(C3 + b0l) -> sX1 ----
    gemm2<4, 4>(g_Wf + OFF_PL0B, sX2, mt0, lane, C3);
    {
        f32x4 bb0 = ldf4(plB0, mt0 * 16 + quad * 4, isbf);
        f32x4 bb1 = ldf4(plB0, (mt0 + 1) * 16 + quad * 4, isbf);
        EPI_RELU_STORE(C3, bb0, bb1, sX1, 4);
    }
    __syncthreads();
    // ---- phase G: out = relu(Hl@plW1 + b1l) ----
    {
        f32x4 bb0 = ldf4(plB1, mt0 * 16 + quad * 4, isbf);
        f32x4 bb1 = ldf4(plB1, (mt0 + 1) * 16 + quad * 4, isbf);
        f32x4 aO[2][4];
#pragma unroll
        for (int ii = 0; ii < 2; ++ii)
#pragma unroll
            for (int nt = 0; nt < 4; ++nt) aO[ii][nt] = (f32x4){0.f, 0.f, 0.f, 0.f};
        gemm2<4, 4>(g_Wf + OFF_PL1, sX1, mt0, lane, aO);
        const size_t NA = (size_t)B_ * N_ * C_;   // 524288
#pragma unroll
        for (int ii = 0; ii < 2; ++ii) {
            int mt = mt0 + ii;
            f32x4 bb = ii ? bb1 : bb0;
#pragma unroll
            for (int nt = 0; nt < 4; ++nt) {
                f32x4 v;
#pragma unroll
                for (int r = 0; r < 4; ++r) { float x = aO[ii][nt][r] + bb[r]; v[r] = x > 0.f ? x : 0.f; }
                store_out4(out, NA + (prow0 + nt * 16 + c) * 128 + mt * 16 + quad * 4, v, isbf);
            }
        }
    }
}

extern "C" void kernel_launch(void* const* d_in, const int* in_sizes, int n_in,
                              void* d_out, int out_size, void* d_ws, size_t ws_size,
                              hipStream_t stream) {
    const void* atom  = d_in[0];
    const void* pairx = d_in[1];
    const void* aaW0 = d_in[2];  const void* aaB0 = d_in[3];
    const void* aaW1 = d_in[4];  const void* aaB1 = d_in[5];
    const void* paW0 = d_in[6];  const void* paB0 = d_in[7];
    const void* paW1 = d_in[8];  const void* paB1 = d_in[9];
    const void* alW0 = d_in[10]; const void* alB0 = d_in[11];
    const void* alW1 = d_in[12]; const void* alB1 = d_in[13];
    const void* apW0 = d_in[14]; const void* apB0 = d_in[15];
    const void* apW1 = d_in[16]; const void* apB1 = d_in[17];
    const void* ppW0 = d_in[18]; const void* ppB0 = d_in[19];
    const void* ppW1 = d_in[20]; const void* ppB1 = d_in[21];
    const void* plW0 = d_in[22]; const void* plB0 = d_in[23];
    const void* plW1 = d_in[24]; const void* plB1 = d_in[25];
    (void)d_ws; (void)ws_size; (void)in_sizes; (void)n_in; (void)out_size;

    detect_k<<<1, 64, 0, stream>>>(atom);
    prep_w<<<102, 256, 0, stream>>>(aaW0, aaW1, apW0, paW0, paW1, alW0, alW1,
                                    apW1, ppW0, ppW1, plW0, plW1);
    atom_pre<<<128, 256, 0, stream>>>(atom, aaB0, aaB1);
    p2a_sum<<<4096, 256, 0, stream>>>(pairx, paB0, paB1);
    atom_layer<<<256, 256, 0, stream>>>(alB0, alB1, d_out);
    pair_fused<<<4096, 256, 0, stream>>>(pairx, apB0, apB1, ppB0, ppB1,
                                         plB0, plB1, d_out);
}

// Round 7
// 299.565 us; speedup vs baseline: 10.2395x; 1.0281x over previous
//
#include <hip/hip_runtime.h>
#include <hip/hip_bf16.h>

typedef unsigned short u16;
typedef unsigned int u32;
typedef __attribute__((ext_vector_type(8))) __bf16 bf16x8;
typedef __attribute__((ext_vector_type(4))) float f32x4;

#define B_ 64
#define N_ 64
#define FA_ 75
#define FP_ 14
#define C_ 128

// ---- static device scratch (fully rewritten every call) ----
__device__ float g_A0[4096 * 128];   // a0 branch, fp32 [row][feat]
__device__ float g_A1[4096 * 128];   // p2a-summed branch, fp32 (written by pair_fused)
__device__ float g_TB[4096 * 256];   // [T | Bo] per atom row, fp32
__device__ u16   g_Wf[208896];       // all weights in A-fragment layout (bf16)

// frag-weight offsets (u16 elements); layout slot = ((mt*KS+ks)*64+lane)*8+j
#define OFF_AA0   0
#define OFF_AA1   12288
#define OFF_APT   28672
#define OFF_APB   40960
#define OFF_PA0   53248
#define OFF_PA1   57344
#define OFF_AL0   73728
#define OFF_AL1   106496
#define OFF_AP1   122880
#define OFF_PP0   139264
#define OFF_PP1   143360
#define OFF_PL0T  159744
#define OFF_PL0B  176128
#define OFF_PL1   192512

__device__ __forceinline__ float bf2f(u16 a) {
    union { u32 u; float f; } v; v.u = ((u32)a) << 16; return v.f;
}
__device__ __forceinline__ u16 f2bf(float f) {
    union { float f; u32 u; } v; v.f = f;
    u32 r = v.u + 0x7fffu + ((v.u >> 16) & 1u);   // RNE
    return (u16)(r >> 16);
}
#if __has_builtin(__builtin_amdgcn_cvt_pk_bf16_f32)
__device__ __forceinline__ u32 f2bf_pk(float a, float b) {
    auto r = __builtin_amdgcn_cvt_pk_bf16_f32(a, b);
    if constexpr (sizeof(r) == 4) {
        union { decltype(r) v; u32 u; } c; c.v = r; return c.u;
    } else {
        return (u32)f2bf(a) | ((u32)f2bf(b) << 16);
    }
}
#else
__device__ __forceinline__ u32 f2bf_pk(float a, float b) {
    return (u32)f2bf(a) | ((u32)f2bf(b) << 16);
}
#endif

// per-wave input dtype detection: bf16 N(0,1) samples have sane exponents in
// the LOW halfword of each u32; fp32 mantissa bits don't. Uniform per wave.
__device__ __forceinline__ bool detect_isbf(const void* __restrict__ atom) {
    u32 wrd = ((const u32*)atom)[threadIdx.x & 63];
    u32 ex = (wrd >> 7) & 0xffu;
    unsigned long long m = __ballot(ex >= 113u && ex <= 133u);
    return __popcll(m) >= 32;
}

__device__ __forceinline__ float ldf(const void* p, size_t i, bool isbf) {
    if (isbf) return bf2f(((const u16*)p)[i]);
    return ((const float*)p)[i];
}
__device__ __forceinline__ f32x4 ldf4(const void* p, int i, bool isbf) {
    f32x4 r;
    if (isbf) {
        const u16* q = (const u16*)p + i;
        r[0] = bf2f(q[0]); r[1] = bf2f(q[1]); r[2] = bf2f(q[2]); r[3] = bf2f(q[3]);
    } else {
        r = *(const f32x4*)((const float*)p + i);
    }
    return r;
}
// pack 8 row elements k0..k0+7 (zero-padded past kmax) into bf16x8 frag word
__device__ __forceinline__ uint4 pack8(const void* p, size_t base, int kmax, int k0, bool isbf) {
    uint4 u;
    if (isbf) {
        const u16* q = (const u16*)p + base;
        u16 h[8];
#pragma unroll
        for (int j = 0; j < 8; ++j) h[j] = (k0 + j < kmax) ? q[k0 + j] : (u16)0;
        u.x = (u32)h[0] | ((u32)h[1] << 16); u.y = (u32)h[2] | ((u32)h[3] << 16);
        u.z = (u32)h[4] | ((u32)h[5] << 16); u.w = (u32)h[6] | ((u32)h[7] << 16);
    } else {
        const float* q = (const float*)p + base;
        float f[8];
#pragma unroll
        for (int j = 0; j < 8; ++j) f[j] = (k0 + j < kmax) ? q[k0 + j] : 0.f;
        u.x = f2bf_pk(f[0], f[1]); u.y = f2bf_pk(f[2], f[3]);
        u.z = f2bf_pk(f[4], f[5]); u.w = f2bf_pk(f[6], f[7]);
    }
    return u;
}

// ---------------- weight prep: global [K][128] -> A-frag layout ----------------
__global__ __launch_bounds__(256) void prep_w(
    const void* atom,
    const void* aaW0, const void* aaW1, const void* apW0,
    const void* paW0, const void* paW1, const void* alW0, const void* alW1,
    const void* apW1, const void* ppW0, const void* ppW1,
    const void* plW0, const void* plW1) {
    const bool isbf = detect_isbf(atom);
    const void* srcs[14] = {aaW0, aaW1, apW0, apW0, paW0, paW1, alW0, alW1,
                            apW1, ppW0, ppW1, plW0, plW0, plW1};
    const int Ktab[14]  = {75, 128, 75, 75, 14, 128, 256, 128, 128, 14, 128, 128, 128, 128};
    const int KStab[14] = {3, 4, 3, 3, 1, 4, 8, 4, 4, 1, 4, 4, 4, 4};
    const int rofft[14] = {0, 0, 0, 75, 0, 0, 0, 0, 0, 0, 0, 0, 128, 0};
    const int baset[14] = {OFF_AA0, OFF_AA1, OFF_APT, OFF_APB, OFF_PA0, OFF_PA1,
                           OFF_AL0, OFF_AL1, OFF_AP1, OFF_PP0, OFF_PP1,
                           OFF_PL0T, OFF_PL0B, OFF_PL1};
    int gid = blockIdx.x * 256 + threadIdx.x;
    int j = 0, s = gid;
    while (j < 14 && s >= KStab[j] * 512) { s -= KStab[j] * 512; ++j; }
    if (j >= 14) return;
    int lane = s & 63, rest = s >> 6;
    int ks = rest % KStab[j], mt = rest / KStab[j];
    int m = mt * 16 + (lane & 15), q = lane >> 4;
    float f[8];
#pragma unroll
    for (int jj = 0; jj < 8; ++jj) {
        int k = ks * 32 + q * 8 + jj;
        f[jj] = (k < Ktab[j]) ? ldf(srcs[j], (size_t)(rofft[j] + k) * 128 + m, isbf) : 0.f;
    }
    uint4 u;
    u.x = f2bf_pk(f[0], f[1]); u.y = f2bf_pk(f[2], f[3]);
    u.z = f2bf_pk(f[4], f[5]); u.w = f2bf_pk(f[6], f[7]);
    *(uint4*)&g_Wf[(size_t)baset[j] + (size_t)s * 8] = u;
}

// ---------------- MFMA GEMM core ----------------
template<int KS, int NT>
__device__ __forceinline__ void gemm2(const u16* __restrict__ wf,
                                      const u16* __restrict__ bF,
                                      int mt0, int lane, f32x4 (&acc)[2][NT]) {
#pragma unroll
    for (int ks = 0; ks < KS; ++ks) {
        bf16x8 a0 = *(const bf16x8*)(wf + (((mt0    ) * KS + ks) * 64 + lane) * 8);
        bf16x8 a1 = *(const bf16x8*)(wf + (((mt0 + 1) * KS + ks) * 64 + lane) * 8);
#pragma unroll
        for (int nt = 0; nt < NT; ++nt) {
            bf16x8 b = *(const bf16x8*)(bF + ((nt * KS + ks) * 64 + lane) * 8);
            acc[0][nt] = __builtin_amdgcn_mfma_f32_16x16x32_bf16(a0, b, acc[0][nt], 0, 0, 0);
            acc[1][nt] = __builtin_amdgcn_mfma_f32_16x16x32_bf16(a1, b, acc[1][nt], 0, 0, 0);
        }
    }
}

// C-frag -> next-layer B-frag store (one uint2 per frag per lane)
__device__ __forceinline__ void frag_store(u16* dstF, int KSd, int nt, int mt, int lane, f32x4 v) {
    int c = lane & 15, quad = lane >> 4;
    int lp = c + 16 * ((2 * mt + (quad >> 1)) & 3);
    int ks = mt >> 1;
    uint2 u; u.x = f2bf_pk(v[0], v[1]); u.y = f2bf_pk(v[2], v[3]);
    *(uint2*)(dstF + (((nt * KSd + ks) * 64 + lp) * 8 + (quad & 1) * 4)) = u;
}

__device__ __forceinline__ void store_out4(void* outp, size_t elem, f32x4 v, bool isbf) {
    if (isbf) {
        uint2 u; u.x = f2bf_pk(v[0], v[1]); u.y = f2bf_pk(v[2], v[3]);
        *(uint2*)((u16*)outp + elem) = u;
    } else {
        *(f32x4*)((float*)outp + elem) = v;
    }
}

#define EPI_RELU_STORE(ACC, BB0, BB1, DST, NTN) do {                             \
    _Pragma("unroll") for (int ii = 0; ii < 2; ++ii) {                           \
        f32x4 bb_ = ii ? (BB1) : (BB0);                                          \
        _Pragma("unroll") for (int nt_ = 0; nt_ < NTN; ++nt_) {                  \
            f32x4 v_;                                                            \
            _Pragma("unroll") for (int r_ = 0; r_ < 4; ++r_) {                   \
                float x_ = ACC[ii][nt_][r_] + bb_[r_];                           \
                v_[r_] = x_ > 0.f ? x_ : 0.f;                                    \
            }                                                                    \
            frag_store(DST, 4, nt_, mt0 + ii, lane, v_);                         \
        }                                                                        \
    }                                                                            \
} while (0)

// ---------------- Kernel: atom branch pre-work (128 blocks, 32 rows each) ---------
__global__ __launch_bounds__(256) void atom_pre(
    const void* __restrict__ atom,
    const void* __restrict__ aaB0, const void* __restrict__ aaB1) {
    __shared__ __align__(16) u16 sXF[2 * 3 * 64 * 8];   // 6KB
    __shared__ __align__(16) u16 sHF[2 * 4 * 64 * 8];   // 8KB
    const bool isbf = detect_isbf(atom);
    const int t = threadIdx.x, lane = t & 63, w = t >> 6;
    const int quad = lane >> 4;
    const int r0g = blockIdx.x * 32;
    for (int s = t; s < 2 * 3 * 64; s += 256) {
        int lane_s = s & 63, rest = s >> 6;
        int ks = rest % 3, nt = rest / 3;
        int n = nt * 16 + (lane_s & 15), q = lane_s >> 4;
        *(uint4*)&sXF[s * 8] = pack8(atom, (size_t)(r0g + n) * FA_, FA_, ks * 32 + q * 8, isbf);
    }
    __syncthreads();
    const int mt0 = 2 * w;
    {
        f32x4 bb0 = ldf4(aaB0, mt0 * 16 + quad * 4, isbf);
        f32x4 bb1 = ldf4(aaB0, (mt0 + 1) * 16 + quad * 4, isbf);
        f32x4 acc[2][2];
#pragma unroll
        for (int ii = 0; ii < 2; ++ii)
#pragma unroll
            for (int nt = 0; nt < 2; ++nt) acc[ii][nt] = (f32x4){0.f, 0.f, 0.f, 0.f};
        gemm2<3, 2>(g_Wf + OFF_AA0, sXF, mt0, lane, acc);
        EPI_RELU_STORE(acc, bb0, bb1, sHF, 2);
    }
    __syncthreads();
    {
        f32x4 bb0 = ldf4(aaB1, mt0 * 16 + quad * 4, isbf);
        f32x4 bb1 = ldf4(aaB1, (mt0 + 1) * 16 + quad * 4, isbf);
        f32x4 acc[2][2];
#pragma unroll
        for (int ii = 0; ii < 2; ++ii)
#pragma unroll
            for (int nt = 0; nt < 2; ++nt) acc[ii][nt] = (f32x4){0.f, 0.f, 0.f, 0.f};
        gemm2<4, 2>(g_Wf + OFF_AA1, sHF, mt0, lane, acc);
        int c = lane & 15;
#pragma unroll
        for (int ii = 0; ii < 2; ++ii) {
            int mt = mt0 + ii;
            f32x4 bb = ii ? bb1 : bb0;
#pragma unroll
            for (int nt = 0; nt < 2; ++nt) {
                f32x4 v;
#pragma unroll
                for (int r = 0; r < 4; ++r) { float x = acc[ii][nt][r] + bb[r]; v[r] = x > 0.f ? x : 0.f; }
                *(f32x4*)&g_A0[(size_t)(r0g + nt * 16 + c) * 128 + mt * 16 + quad * 4] = v;
            }
        }
    }
    {
        f32x4 accT[2][2], accB[2][2];
#pragma unroll
        for (int ii = 0; ii < 2; ++ii)
#pragma unroll
            for (int nt = 0; nt < 2; ++nt) { accT[ii][nt] = (f32x4){0.f,0.f,0.f,0.f}; accB[ii][nt] = (f32x4){0.f,0.f,0.f,0.f}; }
        gemm2<3, 2>(g_Wf + OFF_APT, sXF, mt0, lane, accT);
        gemm2<3, 2>(g_Wf + OFF_APB, sXF, mt0, lane, accB);
        int c = lane & 15;
#pragma unroll
        for (int ii = 0; ii < 2; ++ii) {
            int mt = mt0 + ii;
#pragma unroll
            for (int nt = 0; nt < 2; ++nt) {
                size_t row = (size_t)(r0g + nt * 16 + c);
                *(f32x4*)&g_TB[row * 256 + mt * 16 + quad * 4] = accT[ii][nt];
                *(f32x4*)&g_TB[row * 256 + 128 + mt * 16 + quad * 4] = accB[ii][nt];
            }
        }
    }
}

// ---------------- Kernel: atom_layer (256 blocks, 16 rows each) -------------------
__global__ __launch_bounds__(256) void atom_layer(
    const void* __restrict__ atom,
    const void* __restrict__ alB0, const void* __restrict__ alB1,
    void* __restrict__ out) {
    __shared__ __align__(16) u16 sXF[1 * 8 * 64 * 8];   // 8KB
    __shared__ __align__(16) u16 sHF[1 * 4 * 64 * 8];   // 4KB
    const bool isbf = detect_isbf(atom);
    const int t = threadIdx.x, lane = t & 63, w = t >> 6;
    const int quad = lane >> 4;
    const int r0g = blockIdx.x * 16;
    for (int s = t; s < 8 * 64; s += 256) {
        int lane_s = s & 63, ks = s >> 6;
        int n = lane_s & 15, q = lane_s >> 4;
        int k0 = ks * 32 + q * 8;
        const float* src = (k0 < 128) ? &g_A0[(size_t)(r0g + n) * 128 + k0]
                                      : &g_A1[(size_t)(r0g + n) * 128 + (k0 - 128)];
        f32x4 f0 = *(const f32x4*)src, f1 = *(const f32x4*)(src + 4);
        uint4 u;
        u.x = f2bf_pk(f0[0], f0[1]); u.y = f2bf_pk(f0[2], f0[3]);
        u.z = f2bf_pk(f1[0], f1[1]); u.w = f2bf_pk(f1[2], f1[3]);
        *(uint4*)&sXF[s * 8] = u;
    }
    __syncthreads();
    const int mt0 = 2 * w;
    {
        f32x4 bb0 = ldf4(alB0, mt0 * 16 + quad * 4, isbf);
        f32x4 bb1 = ldf4(alB0, (mt0 + 1) * 16 + quad * 4, isbf);
        f32x4 acc[2][1];
#pragma unroll
        for (int ii = 0; ii < 2; ++ii) acc[ii][0] = (f32x4){0.f, 0.f, 0.f, 0.f};
        gemm2<8, 1>(g_Wf + OFF_AL0, sXF, mt0, lane, acc);
        EPI_RELU_STORE(acc, bb0, bb1, sHF, 1);
    }
    __syncthreads();
    {
        f32x4 bb0 = ldf4(alB1, mt0 * 16 + quad * 4, isbf);
        f32x4 bb1 = ldf4(alB1, (mt0 + 1) * 16 + quad * 4, isbf);
        f32x4 acc[2][1];
#pragma unroll
        for (int ii = 0; ii < 2; ++ii) acc[ii][0] = (f32x4){0.f, 0.f, 0.f, 0.f};
        gemm2<4, 1>(g_Wf + OFF_AL1, sHF, mt0, lane, acc);
        int c = lane & 15;
#pragma unroll
        for (int ii = 0; ii < 2; ++ii) {
            int mt = mt0 + ii;
            f32x4 bb = ii ? bb1 : bb0;
            f32x4 v;
#pragma unroll
            for (int r = 0; r < 4; ++r) { float x = acc[ii][0][r] + bb[r]; v[r] = x > 0.f ? x : 0.f; }
            store_out4(out, (size_t)(r0g + c) * 128 + mt * 16 + quad * 4, v, isbf);
        }
    }
}

// ---------------- Kernel: fused pair branch + PairToAtom (4096 blocks) ------------
__global__ __launch_bounds__(256, 3) void pair_fused(
    const void* __restrict__ atom,
    const void* __restrict__ pairx,
    const void* __restrict__ apB0, const void* __restrict__ apB1,
    const void* __restrict__ ppB0, const void* __restrict__ ppB1,
    const void* __restrict__ plB0, const void* __restrict__ plB1,
    const void* __restrict__ paB0, const void* __restrict__ paB1,
    void* __restrict__ out) {
    __shared__ __align__(16) u16 sX1[4 * 4 * 64 * 8];   // 16KB  H0 -> Hp -> Hl
    __shared__ __align__(16) u16 sX2[4 * 4 * 64 * 8];   // 16KB  H1 -> HpA
    __shared__ __align__(16) u16 sR [4 * 4 * 64 * 8];   // 16KB  P0 -> P1
    __shared__ __align__(16) u16 sPr[4 * 1 * 64 * 8];   // 4KB   pair_x frags
    const bool isbf = detect_isbf(atom);
    const int t = threadIdx.x, lane = t & 63, w = t >> 6;
    const int quad = lane >> 4, c = lane & 15;
    const int bx = blockIdx.x;
    const int b = bx >> 6, i = bx & 63;
    const int trow = b * 64;
    const size_t prow0 = (size_t)b * 4096 + (size_t)i * 64;
    const int mt0 = 2 * w;

    // ---- stage (no barriers yet): Pr frags + H0/H1 built from registers ----
    {
        int lane_s = t & 63, nt = t >> 6;
        int n = nt * 16 + (lane_s & 15), q = lane_s >> 4;
        *(uint4*)&sPr[t * 8] = pack8(pairx, (prow0 + n) * FP_, FP_, q * 8, isbf);
    }
    {
        const int ksg = t >> 6;               // this thread's ks segment
        const int k0 = ksg * 32 + quad * 8;   // fixed 8-wide k window
        const int rc = c;                     // row-class within each 16-row group
        const float* TBi = &g_TB[(size_t)(trow + i) * 256 + k0];
        f32x4 t0 = *(const f32x4*)TBi,        t1 = *(const f32x4*)(TBi + 4);
        f32x4 o0 = *(const f32x4*)(TBi + 128), o1 = *(const f32x4*)(TBi + 132);
        f32x4 b0a = ldf4(apB0, k0, isbf), b0b = ldf4(apB0, k0 + 4, isbf);
        float Tip[8], Bip[8];
#pragma unroll
        for (int r = 0; r < 4; ++r) {
            Tip[r] = t0[r] + b0a[r]; Tip[4 + r] = t1[r] + b0b[r];
            Bip[r] = o0[r] + b0a[r]; Bip[4 + r] = o1[r] + b0b[r];
        }
#pragma unroll
        for (int nt = 0; nt < 4; ++nt) {
            int n = nt * 16 + rc;
            const float* Bj = &g_TB[(size_t)(trow + n) * 256 + k0];
            f32x4 j0 = *(const f32x4*)Bj,        j1 = *(const f32x4*)(Bj + 4);
            f32x4 j2 = *(const f32x4*)(Bj + 128), j3 = *(const f32x4*)(Bj + 132);
            float v0[8], v1[8];
#pragma unroll
            for (int r = 0; r < 4; ++r) {
                float x0 = Tip[r] + j2[r];      v0[r]     = x0 > 0.f ? x0 : 0.f;  // H0
                float x1 = Tip[4 + r] + j3[r];  v0[4 + r] = x1 > 0.f ? x1 : 0.f;
                float y0 = j0[r] + Bip[r];      v1[r]     = y0 > 0.f ? y0 : 0.f;  // H1
                float y1 = j1[r] + Bip[4 + r];  v1[4 + r] = y1 > 0.f ? y1 : 0.f;
            }
            uint4 u0, u1;
            u0.x = f2bf_pk(v0[0], v0[1]); u0.y = f2bf_pk(v0[2], v0[3]);
            u0.z = f2bf_pk(v0[4], v0[5]); u0.w = f2bf_pk(v0[6], v0[7]);
            u1.x = f2bf_pk(v1[0], v1[1]); u1.y = f2bf_pk(v1[2], v1[3]);
            u1.z = f2bf_pk(v1[4], v1[5]); u1.w = f2bf_pk(v1[6], v1[7]);
            int slot = ((nt * 4 + ksg) * 64 + lane) * 8;
            *(uint4*)&sX1[slot] = u0;
            *(uint4*)&sX2[slot] = u1;
        }
    }
    __syncthreads();
    // ---- phase C: P0 = relu(H0@apW1+b1)+relu(H1@apW1+b1) -> sR ;
    //               aH = Pr@ppW0, aPA = Pr@paW0 (regs, carried across barrier) ----
    {
        f32x4 bb0 = ldf4(apB1, mt0 * 16 + quad * 4, isbf);
        f32x4 bb1 = ldf4(apB1, (mt0 + 1) * 16 + quad * 4, isbf);
        f32x4 aA[2][4], aB[2][4];
#pragma unroll
        for (int ii = 0; ii < 2; ++ii)
#pragma unroll
            for (int nt = 0; nt < 4; ++nt) { aA[ii][nt] = (f32x4){0.f,0.f,0.f,0.f}; aB[ii][nt] = (f32x4){0.f,0.f,0.f,0.f}; }
        gemm2<4, 4>(g_Wf + OFF_AP1, sX1, mt0, lane, aA);
        gemm2<4, 4>(g_Wf + OFF_AP1, sX2, mt0, lane, aB);
#pragma unroll
        for (int ii = 0; ii < 2; ++ii) {
            int mt = mt0 + ii;
            f32x4 bb = ii ? bb1 : bb0;
#pragma unroll
            for (int nt = 0; nt < 4; ++nt) {
                f32x4 v;
#pragma unroll
                for (int r = 0; r < 4; ++r) {
                    float x = aA[ii][nt][r] + bb[r];
                    float y = aB[ii][nt][r] + bb[r];
                    v[r] = (x > 0.f ? x : 0.f) + (y > 0.f ? y : 0.f);
                }
                frag_store(sR, 4, nt, mt, lane, v);
            }
        }
    }
    f32x4 aH[2][4], aPA[2][4];
#pragma unroll
    for (int ii = 0; ii < 2; ++ii)
#pragma unroll
        for (int nt = 0; nt < 4; ++nt) { aH[ii][nt] = (f32x4){0.f,0.f,0.f,0.f}; aPA[ii][nt] = (f32x4){0.f,0.f,0.f,0.f}; }
    gemm2<1, 4>(g_Wf + OFF_PP0, sPr, mt0, lane, aH);
    gemm2<1, 4>(g_Wf + OFF_PA0, sPr, mt0, lane, aPA);
    __syncthreads();
    // ---- phase D: C3 = P0@plW0_top ; Hp = relu(aH+b0p) -> sX1 ; HpA = relu(aPA+b0pa) -> sX2
    f32x4 C3[2][4];
#pragma unroll
    for (int ii = 0; ii < 2; ++ii)
#pragma unroll
        for (int nt = 0; nt < 4; ++nt) C3[ii][nt] = (f32x4){0.f, 0.f, 0.f, 0.f};
    gemm2<4, 4>(g_Wf + OFF_PL0T, sR, mt0, lane, C3);
    {
        f32x4 bb0 = ldf4(ppB0, mt0 * 16 + quad * 4, isbf);
        f32x4 bb1 = ldf4(ppB0, (mt0 + 1) * 16 + quad * 4, isbf);
        EPI_RELU_STORE(aH, bb0, bb1, sX1, 4);
    }
    {
        f32x4 bb0 = ldf4(paB0, mt0 * 16 + quad * 4, isbf);
        f32x4 bb1 = ldf4(paB0, (mt0 + 1) * 16 + quad * 4, isbf);
        EPI_RELU_STORE(aPA, bb0, bb1, sX2, 4);
    }
    __syncthreads();
    // ---- phase E: P1 = relu(Hp@ppW1+b1p) -> sR ;
    //               aA1 = HpA@paW1 -> bias/relu/sum over rows -> g_A1 ----
    {
        f32x4 aP[2][4], aA1[2][4];
#pragma unroll
        for (int ii = 0; ii < 2; ++ii)
#pragma unroll
            for (int nt = 0; nt < 4; ++nt) { aP[ii][nt] = (f32x4){0.f,0.f,0.f,0.f}; aA1[ii][nt] = (f32x4){0.f,0.f,0.f,0.f}; }
        gemm2<4, 4>(g_Wf + OFF_PP1, sX1, mt0, lane, aP);
        gemm2<4, 4>(g_Wf + OFF_PA1, sX2, mt0, lane, aA1);
        {
            f32x4 pb0 = ldf4(paB1, mt0 * 16 + quad * 4, isbf);
            f32x4 pb1 = ldf4(paB1, (mt0 + 1) * 16 + quad * 4, isbf);
#pragma unroll
            for (int ii = 0; ii < 2; ++ii) {
                int mt = mt0 + ii;
                f32x4 bb = ii ? pb1 : pb0;
                f32x4 ssum = (f32x4){0.f, 0.f, 0.f, 0.f};
#pragma unroll
                for (int nt = 0; nt < 4; ++nt)
#pragma unroll
                    for (int r = 0; r < 4; ++r) {
                        float x = aA1[ii][nt][r] + bb[r];
                        ssum[r] += (x > 0.f ? x : 0.f);
                    }
#pragma unroll
                for (int m = 1; m < 16; m <<= 1)
#pragma unroll
                    for (int r = 0; r < 4; ++r) ssum[r] += __shfl_xor(ssum[r], m, 64);
                if ((lane & 15) == 0)
                    *(f32x4*)&g_A1[(size_t)bx * 128 + mt * 16 + quad * 4] = ssum;
            }
        }
        f32x4 bb0 = ldf4(ppB1, mt0 * 16 + quad * 4, isbf);
        f32x4 bb1 = ldf4(ppB1, (mt0 + 1) * 16 + quad * 4, isbf);
        EPI_RELU_STORE(aP, bb0, bb1, sR, 4);
    }
    __syncthreads();
    // ---- phase F: C3 += P1@plW0_bot ; Hl = relu(C3 + b0l) -> sX1 ----
    gemm2<4, 4>(g_Wf + OFF_PL0B, sR, mt0, lane, C3);
    {
        f32x4 bb0 = ldf4(plB0, mt0 * 16 + quad * 4, isbf);
        f32x4 bb1 = ldf4(plB0, (mt0 + 1) * 16 + quad * 4, isbf);
        EPI_RELU_STORE(C3, bb0, bb1, sX1, 4);
    }
    __syncthreads();
    // ---- phase G: out = relu(Hl@plW1 + b1l) ----
    {
        f32x4 bb0 = ldf4(plB1, mt0 * 16 + quad * 4, isbf);
        f32x4 bb1 = ldf4(plB1, (mt0 + 1) * 16 + quad * 4, isbf);
        f32x4 aO[2][4];
#pragma unroll
        for (int ii = 0; ii < 2; ++ii)
#pragma unroll
            for (int nt = 0; nt < 4; ++nt) aO[ii][nt] = (f32x4){0.f, 0.f, 0.f, 0.f};
        gemm2<4, 4>(g_Wf + OFF_PL1, sX1, mt0, lane, aO);
        const size_t NA = (size_t)B_ * N_ * C_;   // 524288
#pragma unroll
        for (int ii = 0; ii < 2; ++ii) {
            int mt = mt0 + ii;
            f32x4 bb = ii ? bb1 : bb0;
#pragma unroll
            for (int nt = 0; nt < 4; ++nt) {
                f32x4 v;
#pragma unroll
                for (int r = 0; r < 4; ++r) { float x = aO[ii][nt][r] + bb[r]; v[r] = x > 0.f ? x : 0.f; }
                store_out4(out, NA + (prow0 + nt * 16 + c) * 128 + mt * 16 + quad * 4, v, isbf);
            }
        }
    }
}

extern "C" void kernel_launch(void* const* d_in, const int* in_sizes, int n_in,
                              void* d_out, int out_size, void* d_ws, size_t ws_size,
                              hipStream_t stream) {
    const void* atom  = d_in[0];
    const void* pairx = d_in[1];
    const void* aaW0 = d_in[2];  const void* aaB0 = d_in[3];
    const void* aaW1 = d_in[4];  const void* aaB1 = d_in[5];
    const void* paW0 = d_in[6];  const void* paB0 = d_in[7];
    const void* paW1 = d_in[8];  const void* paB1 = d_in[9];
    const void* alW0 = d_in[10]; const void* alB0 = d_in[11];
    const void* alW1 = d_in[12]; const void* alB1 = d_in[13];
    const void* apW0 = d_in[14]; const void* apB0 = d_in[15];
    const void* apW1 = d_in[16]; const void* apB1 = d_in[17];
    const void* ppW0 = d_in[18]; const void* ppB0 = d_in[19];
    const void* ppW1 = d_in[20]; const void* ppB1 = d_in[21];
    const void* plW0 = d_in[22]; const void* plB0 = d_in[23];
    const void* plW1 = d_in[24]; const void* plB1 = d_in[25];
    (void)d_ws; (void)ws_size; (void)in_sizes; (void)n_in; (void)out_size;

    prep_w<<<102, 256, 0, stream>>>(atom, aaW0, aaW1, apW0, paW0, paW1, alW0, alW1,
                                    apW1, ppW0, ppW1, plW0, plW1);
    atom_pre<<<128, 256, 0, stream>>>(atom, aaB0, aaB1);
    pair_fused<<<4096, 256, 0, stream>>>(atom, pairx, apB0, apB1, ppB0, ppB1,
                                         plB0, plB1, paB0, paB1, d_out);
    atom_layer<<<256, 256, 0, stream>>>(atom, alB0, alB1, d_out);
}